// Round 5
// baseline (179.876 us; speedup 1.0000x reference)
//
#include <hip/hip_runtime.h>
#include <hip/hip_bf16.h>

// Problem constants: B=8, N=1024, C=768, H=12, D=64, M=128
#define PB 8
#define PN 1024
#define PC 768
#define PH 12
#define PD 64
#define PM 128
#define SQ 0.35355339059327373f      // (D^-0.5)^0.5 = D^-0.25
#define MSCALE 0.08838834764831843f  // M^-0.5

typedef _Float16 f16;
typedef f16 f16x8 __attribute__((ext_vector_type(8)));
typedef f16 f16x4 __attribute__((ext_vector_type(4)));
typedef float f32x4 __attribute__((ext_vector_type(4)));

#define GLL(src, dst) __builtin_amdgcn_global_load_lds( \
    (const __attribute__((address_space(1))) void*)(src), \
    (__attribute__((address_space(3))) void*)(dst), 16, 0, 0)

// ---------------- conversions, one launch ----------------
// [0,8192): x; [8192,10496): qkv_w; [10496,11264): proj_w; [11264,11276): Rt
__global__ __launch_bounds__(192) void conv_all(
        const float* __restrict__ x, const float* __restrict__ qkv_w,
        const float* __restrict__ proj_w, const float* __restrict__ rm,
        f16* __restrict__ Ax, f16* __restrict__ Bqk, f16* __restrict__ Bp,
        f16* __restrict__ Rt)
{
    const int bid = blockIdx.x;
    const int t = threadIdx.x;
    if (bid < 11264) {
        const float* src; f16* dst; int r;
        if (bid < 8192)       { src = x;      dst = Ax;  r = bid; }
        else if (bid < 10496) { src = qkv_w;  dst = Bqk; r = bid - 8192; }
        else                  { src = proj_w; dst = Bp;  r = bid - 10496; }
        const int c = t * 4;
        float4 v = *(const float4*)&src[(size_t)r * PC + c];
        f16x4 hv;
        hv.x = (f16)v.x; hv.y = (f16)v.y; hv.z = (f16)v.z; hv.w = (f16)v.w;
        *(f16x4*)&dst[(size_t)r * PC + c] = hv;
    } else {
        const int h = bid - 11264;
        for (int e = t; e < PD * PM; e += 192)
            Rt[(size_t)h * 8192 + e] = (f16)rm[(size_t)h * 8192 + (e & 63) * PM + (e >> 6)];
    }
}

// ---------------- fused qkv GEMM: 8-wave (512t) occupancy variant ----------------
// Same 128x128 tile, same 2-barrier-per-K-step loop, same swizzle as the proven
// 4-wave kernel. Waves arranged 4M x 2N, per-wave 32x64 output: acc=32 AGPR
// (was 64) -> ~90 unified regs/thread (was ~148) -> 2x the resident waves/CU.
// In-session evidence r1-r4: schedule changes are all neutral (~56us); the
// anomaly is Occupancy 25% -> this attacks exactly that.
__global__ __launch_bounds__(512) void gemm_qkv(
        const f16* __restrict__ A,    // [8192][768]
        const f16* __restrict__ Bm,   // [2304][768]
        f16* __restrict__ zq, f16* __restrict__ zk, f16* __restrict__ vh,
        float* __restrict__ sqq, float* __restrict__ sqk)
{
    __shared__ f16 As[128 * 64];
    __shared__ f16 Bs[128 * 64];
    const int t = threadIdx.x;
    const int wave = t >> 6, lane = t & 63;
    const int wm = wave >> 1, wn = wave & 1;     // 4M x 2N
    const int bi = blockIdx.x * 128, bj = blockIdx.y * 128;

    f32x4 acc[2][4] = {};

    // staging: each wave stages its own 16-row slab of A and B (2 GLL each).
    // XOR-key check: for slab base = wave*16 (mult of 16), key((base+rowi))
    // = ((base+rowi)>>1)&7 = (lane>>4)&3 for rows 0-7, ^4 for rows 8-15.
    const int rowi = lane >> 3;
    const int cb = (lane & 7) ^ ((lane >> 4) & 3);
    const f16* ApE = A + (size_t)(bi + wave * 16 + rowi) * PC + cb * 8;
    const f16* ApO = A + (size_t)(bi + wave * 16 + rowi) * PC + (cb ^ 4) * 8;
    const f16* BpE = Bm + (size_t)(bj + wave * 16 + rowi) * PC + cb * 8;
    const f16* BpO = Bm + (size_t)(bj + wave * 16 + rowi) * PC + (cb ^ 4) * 8;
    f16* AsB = &As[wave * 16 * 64];
    f16* BsB = &Bs[wave * 16 * 64];

    const int q4 = lane >> 4;
    for (int kt = 0; kt < 12; ++kt) {
        const int k0 = kt * 64;
        __syncthreads();
        GLL(ApE + k0,                   AsB);
        GLL(ApO + k0 + (size_t)8 * PC,  AsB + 8 * 64);
        GLL(BpE + k0,                   BsB);
        GLL(BpO + k0 + (size_t)8 * PC,  BsB + 8 * 64);
        __syncthreads();

        #pragma unroll
        for (int kh = 0; kh < 2; ++kh) {
            f16x8 af[2], bf[4];
            #pragma unroll
            for (int i = 0; i < 2; ++i) {
                const int r = wm * 32 + i * 16 + (lane & 15);
                const int p = (kh * 4 + q4) ^ ((r >> 1) & 7);
                af[i] = *(const f16x8*)&As[r * 64 + p * 8];
            }
            #pragma unroll
            for (int j = 0; j < 4; ++j) {
                const int r = wn * 64 + j * 16 + (lane & 15);
                const int p = (kh * 4 + q4) ^ ((r >> 1) & 7);
                bf[j] = *(const f16x8*)&Bs[r * 64 + p * 8];
            }
            #pragma unroll
            for (int i = 0; i < 2; ++i)
                #pragma unroll
                for (int j = 0; j < 4; ++j)
                    acc[i][j] = __builtin_amdgcn_mfma_f32_16x16x32_f16(af[i], bf[j], acc[i][j], 0, 0, 0);
        }
    }

    // epilogue: identical mapping, per-wave rows = 32 (i spans 2), cols = 64 (full head)
    const int quad = lane >> 4, cc = lane & 15;
    const int colbase = bj + wn * 64;
    const int b = bi >> 10;
    if (colbase < 1536) {
        const int which = colbase >= 768;
        const int h = (colbase - which * 768) >> 6;
        f16* zdst = which ? zk : zq;
        float* sdst = which ? sqk : sqq;
        const size_t bh = (size_t)(b * PH + h);
        #pragma unroll
        for (int i = 0; i < 2; ++i) {
            const int row0 = bi + wm * 32 + i * 16 + quad * 4;
            #pragma unroll
            for (int r = 0; r < 4; ++r) {
                const int n = (row0 + r) & 1023;
                f16 zh[4]; float psq = 0.f;
                #pragma unroll
                for (int j = 0; j < 4; ++j) {
                    zh[j] = (f16)(acc[i][j][r] * SQ);
                    float zf = (float)zh[j];
                    psq += zf * zf;
                }
                psq += __shfl_xor(psq, 1, 64);
                psq += __shfl_xor(psq, 2, 64);
                psq += __shfl_xor(psq, 4, 64);
                psq += __shfl_xor(psq, 8, 64);
                if (cc == 0) sdst[(bh << 10) + n] = 0.5f * psq;
                f16* zp = zdst + (((bh << 10) + n) << 6);
                #pragma unroll
                for (int j = 0; j < 4; ++j) zp[j * 16 + cc] = zh[j];
            }
        }
    } else {
        const int h = (colbase - 1536) >> 6;
        const size_t bh = (size_t)(b * PH + h);
        #pragma unroll
        for (int i = 0; i < 2; ++i) {
            const int row0 = bi + wm * 32 + i * 16 + quad * 4;
            #pragma unroll
            for (int r = 0; r < 4; ++r) {
                const int n = (row0 + r) & 1023;
                f16* vp = vh + (((bh << 10) + n) << 6);
                #pragma unroll
                for (int j = 0; j < 4; ++j) vp[j * 16 + cc] = (f16)acc[i][j][r];
            }
        }
    }
}

// ---------------- fused feat(k) + kf^T@V partial + colsum -> per-nt partials (NO atomics) ----------------
__global__ __launch_bounds__(256) void feat_kv(
        const f16* __restrict__ zk, const f16* __restrict__ Rt,
        const float* __restrict__ sqk, const f16* __restrict__ vh,
        float* __restrict__ kvpA, float* __restrict__ kvpB, float* __restrict__ sfp)
{
    __shared__ __align__(16) char smem[52224];
    f16* As = (f16*)smem;              // stage z [128][64] (16KB)
    f16* Bs = (f16*)(smem + 16384);    // stage Rt [128][64] (16KB)
    f16* Pt = (f16*)smem;              // [128 m][136 n] aliases stages
    f16* vT = (f16*)(smem + 34816);    // [64 d][136 n]
    __shared__ float sqs[128];

    const int t = threadIdx.x;
    const int wave = t >> 6, lane = t & 63;
    const int wm = wave >> 1, wn = wave & 1;
    const int nt = blockIdx.x, bh = blockIdx.y;
    const int h = bh % PH;

    const f16* A = zk + (((size_t)bh << 10) + nt * 128) * 64;
    const f16* Bm = Rt + (size_t)h * (PM * PD);

    if (t < 128) sqs[t] = sqk[((size_t)bh << 10) + nt * 128 + t];

    const int rowi = lane >> 3;
    const int cb = (lane & 7) ^ ((lane >> 4) & 3);
    const f16* ApE = A + (size_t)(wave * 32 + rowi) * 64 + cb * 8;
    const f16* ApO = A + (size_t)(wave * 32 + rowi) * 64 + (cb ^ 4) * 8;
    const f16* BpE = Bm + (size_t)(wave * 32 + rowi) * 64 + cb * 8;
    const f16* BpO = Bm + (size_t)(wave * 32 + rowi) * 64 + (cb ^ 4) * 8;
    f16* AsB = &As[wave * 32 * 64];
    f16* BsB = &Bs[wave * 32 * 64];
    GLL(ApE,            AsB);
    GLL(ApO + 8 * 64,   AsB + 8 * 64);
    GLL(ApE + 16 * 64,  AsB + 16 * 64);
    GLL(ApO + 24 * 64,  AsB + 24 * 64);
    GLL(BpE,            BsB);
    GLL(BpO + 8 * 64,   BsB + 8 * 64);
    GLL(BpE + 16 * 64,  BsB + 16 * 64);
    GLL(BpO + 24 * 64,  BsB + 24 * 64);
    __syncthreads();

    const int q4 = lane >> 4;
    f32x4 acc[4][4] = {};
    #pragma unroll
    for (int kh = 0; kh < 2; ++kh) {
        f16x8 af[4], bf[4];
        #pragma unroll
        for (int i = 0; i < 4; ++i) {
            const int r = wm * 64 + i * 16 + (lane & 15);
            const int p = (kh * 4 + q4) ^ ((r >> 1) & 7);
            af[i] = *(const f16x8*)&As[r * 64 + p * 8];
        }
        #pragma unroll
        for (int j = 0; j < 4; ++j) {
            const int r = wn * 64 + j * 16 + (lane & 15);
            const int p = (kh * 4 + q4) ^ ((r >> 1) & 7);
            bf[j] = *(const f16x8*)&Bs[r * 64 + p * 8];
        }
        #pragma unroll
        for (int i = 0; i < 4; ++i)
            #pragma unroll
            for (int j = 0; j < 4; ++j)
                acc[i][j] = __builtin_amdgcn_mfma_f32_16x16x32_f16(af[i], bf[j], acc[i][j], 0, 0, 0);
    }

    const int quad = lane >> 4, cc = lane & 15;
    __syncthreads();

    #pragma unroll
    for (int i = 0; i < 4; ++i) {
        #pragma unroll
        for (int j = 0; j < 4; ++j) {
            const int col = wn * 64 + j * 16 + cc;
            #pragma unroll
            for (int r = 0; r < 4; ++r) {
                const int rl = wm * 64 + i * 16 + quad * 4 + r;
                Pt[col * 136 + rl] = (f16)(__expf(acc[i][j][r] - sqs[rl]) * MSCALE);
            }
        }
    }
    {
        const int vn = t >> 1;
        const int vhf = (t & 1) * 32;
        const f16* vbase = vh + (((size_t)bh << 10) + nt * 128 + vn) * 64 + vhf;
        #pragma unroll
        for (int k = 0; k < 4; ++k) {
            f16x8 vv = *(const f16x8*)&vbase[k * 8];
            #pragma unroll
            for (int e = 0; e < 8; ++e)
                vT[(vhf + k * 8 + e) * 136 + vn] = vv[e];
        }
    }
    __syncthreads();

    f32x4 acc2[4][2] = {};
    #pragma unroll
    for (int kt = 0; kt < 4; ++kt) {
        const int kb = kt * 32 + (lane >> 4) * 8;
        f16x8 af2[4], bf2[2];
        #pragma unroll
        for (int i = 0; i < 4; ++i)
            af2[i] = *(const f16x8*)&Pt[(wm * 64 + i * 16 + (lane & 15)) * 136 + kb];
        #pragma unroll
        for (int j = 0; j < 2; ++j)
            bf2[j] = *(const f16x8*)&vT[(wn * 32 + j * 16 + (lane & 15)) * 136 + kb];
        #pragma unroll
        for (int i = 0; i < 4; ++i)
            #pragma unroll
            for (int j = 0; j < 2; ++j)
                acc2[i][j] = __builtin_amdgcn_mfma_f32_16x16x32_f16(af2[i], bf2[j], acc2[i][j], 0, 0, 0);
    }

    // plain stores to this nt's partial buffer (each element written exactly once per block)
    float* kvo = ((nt < 4) ? (kvpA + (size_t)nt * 786432)
                           : (kvpB + (size_t)(nt - 4) * 786432)) + (size_t)bh * 8192;
    #pragma unroll
    for (int i = 0; i < 4; ++i) {
        #pragma unroll
        for (int j = 0; j < 2; ++j) {
            const int d = wn * 32 + j * 16 + cc;
            #pragma unroll
            for (int r = 0; r < 4; ++r) {
                const int m = wm * 64 + i * 16 + quad * 4 + r;
                kvo[m * 64 + d] = acc2[i][j][r];
            }
        }
    }
    {
        const int sm = t >> 1, shf = (t & 1) * 64;
        float sp = 0.f;
        #pragma unroll
        for (int k = 0; k < 8; ++k) {
            f16x8 pv = *(const f16x8*)&Pt[sm * 136 + shf + k * 8];
            #pragma unroll
            for (int e = 0; e < 8; ++e) sp += (float)pv[e];
        }
        sp += __shfl_xor(sp, 1, 64);
        if ((t & 1) == 0) sfp[((size_t)nt * 96 + bh) * 128 + sm] = sp;
    }
}

// ---------------- reduce the 8 per-nt partials -> kvf, sf (BW-bound, ~28 MB) ----------------
__global__ __launch_bounds__(256) void kv_reduce(
        const float* __restrict__ kvpA, const float* __restrict__ kvpB,
        const float* __restrict__ sfp, float* __restrict__ kvf, float* __restrict__ sf)
{
    const int bh = blockIdx.x;
    if (blockIdx.y == 8) {
        const int t = threadIdx.x;
        if (t < 128) {
            float s = 0.f;
            #pragma unroll
            for (int nt = 0; nt < 8; ++nt)
                s += sfp[((size_t)nt * 96 + bh) * 128 + t];
            sf[(size_t)bh * 128 + t] = s;
        }
        return;
    }
    const size_t base = (size_t)bh * 8192 + blockIdx.y * 1024 + threadIdx.x * 4;
    float4 s = *(const float4*)&kvpA[base];
    #pragma unroll
    for (int nt = 1; nt < 4; ++nt) {
        float4 v = *(const float4*)&kvpA[(size_t)nt * 786432 + base];
        s.x += v.x; s.y += v.y; s.z += v.z; s.w += v.w;
    }
    #pragma unroll
    for (int nt = 0; nt < 4; ++nt) {
        float4 v = *(const float4*)&kvpB[(size_t)nt * 786432 + base];
        s.x += v.x; s.y += v.y; s.z += v.z; s.w += v.w;
    }
    *(float4*)&kvf[base] = s;
}

// ---------------- fused feat(q) + denom + P@KV + divide (BK=64, 1 stage) ----------------
__global__ __launch_bounds__(256) void feat_apply(
        const f16* __restrict__ zq, const f16* __restrict__ Rt,
        const float* __restrict__ sqq, const float* __restrict__ kvf,
        const float* __restrict__ sf, f16* __restrict__ ohA)
{
    __shared__ __align__(16) char smem[52224];
    f16* As = (f16*)smem;
    f16* Bs = (f16*)(smem + 16384);
    f16* Pn = (f16*)smem;              // [128 n][136 m]
    f16* kvT = (f16*)(smem + 34816);   // [64 d][136 m]
    __shared__ float sqs[128], ssm[128], dns[128];

    const int t = threadIdx.x;
    const int wave = t >> 6, lane = t & 63;
    const int wm = wave >> 1, wn = wave & 1;
    const int nt = blockIdx.x, bh = blockIdx.y;
    const int b = bh / PH, h = bh % PH;

    const f16* A = zq + (((size_t)bh << 10) + nt * 128) * 64;
    const f16* Bm = Rt + (size_t)h * (PM * PD);

    if (t < 128) {
        sqs[t] = sqq[((size_t)bh << 10) + nt * 128 + t];
        ssm[t] = sf[(size_t)bh * 128 + t];
    }

    const int rowi = lane >> 3;
    const int cb = (lane & 7) ^ ((lane >> 4) & 3);
    const f16* ApE = A + (size_t)(wave * 32 + rowi) * 64 + cb * 8;
    const f16* ApO = A + (size_t)(wave * 32 + rowi) * 64 + (cb ^ 4) * 8;
    const f16* BpE = Bm + (size_t)(wave * 32 + rowi) * 64 + cb * 8;
    const f16* BpO = Bm + (size_t)(wave * 32 + rowi) * 64 + (cb ^ 4) * 8;
    f16* AsB = &As[wave * 32 * 64];
    f16* BsB = &Bs[wave * 32 * 64];
    GLL(ApE,            AsB);
    GLL(ApO + 8 * 64,   AsB + 8 * 64);
    GLL(ApE + 16 * 64,  AsB + 16 * 64);
    GLL(ApO + 24 * 64,  AsB + 24 * 64);
    GLL(BpE,            BsB);
    GLL(BpO + 8 * 64,   BsB + 8 * 64);
    GLL(BpE + 16 * 64,  BsB + 16 * 64);
    GLL(BpO + 24 * 64,  BsB + 24 * 64);
    __syncthreads();

    const int q4 = lane >> 4;
    f32x4 acc[4][4] = {};
    #pragma unroll
    for (int kh = 0; kh < 2; ++kh) {
        f16x8 af[4], bf[4];
        #pragma unroll
        for (int i = 0; i < 4; ++i) {
            const int r = wm * 64 + i * 16 + (lane & 15);
            const int p = (kh * 4 + q4) ^ ((r >> 1) & 7);
            af[i] = *(const f16x8*)&As[r * 64 + p * 8];
        }
        #pragma unroll
        for (int j = 0; j < 4; ++j) {
            const int r = wn * 64 + j * 16 + (lane & 15);
            const int p = (kh * 4 + q4) ^ ((r >> 1) & 7);
            bf[j] = *(const f16x8*)&Bs[r * 64 + p * 8];
        }
        #pragma unroll
        for (int i = 0; i < 4; ++i)
            #pragma unroll
            for (int j = 0; j < 4; ++j)
                acc[i][j] = __builtin_amdgcn_mfma_f32_16x16x32_f16(af[i], bf[j], acc[i][j], 0, 0, 0);
    }

    const int quad = lane >> 4, cc = lane & 15;
    __syncthreads();

    #pragma unroll
    for (int i = 0; i < 4; ++i) {
        #pragma unroll
        for (int j = 0; j < 4; ++j) {
            const int col = wn * 64 + j * 16 + cc;
            #pragma unroll
            for (int r = 0; r < 4; ++r) {
                const int rl = wm * 64 + i * 16 + quad * 4 + r;
                Pn[rl * 136 + col] = (f16)(__expf(acc[i][j][r] - sqs[rl]) * MSCALE);
            }
        }
    }
    {
        const int m = t >> 1;
        const int dh2 = (t & 1) * 32;
        const float* kvb = kvf + ((size_t)bh * 128 + m) * 64 + dh2;
        #pragma unroll
        for (int k = 0; k < 8; ++k) {
            float4 k4 = *(const float4*)&kvb[k * 4];
            kvT[(dh2 + k * 4 + 0) * 136 + m] = (f16)k4.x;
            kvT[(dh2 + k * 4 + 1) * 136 + m] = (f16)k4.y;
            kvT[(dh2 + k * 4 + 2) * 136 + m] = (f16)k4.z;
            kvT[(dh2 + k * 4 + 3) * 136 + m] = (f16)k4.w;
        }
    }
    __syncthreads();

    {
        const int n = t >> 1, mh = (t & 1) * 64;
        float p = 0.f;
        #pragma unroll
        for (int k = 0; k < 8; ++k) {
            f16x8 pv = *(const f16x8*)&Pn[n * 136 + mh + k * 8];
            #pragma unroll
            for (int e = 0; e < 8; ++e)
                p += (float)pv[e] * ssm[mh + k * 8 + e];
        }
        p += __shfl_xor(p, 1, 64);
        if ((t & 1) == 0) dns[n] = (p < 1e-12f) ? 1e-12f : p;
    }
    __syncthreads();

    f32x4 acc3[4][2] = {};
    #pragma unroll
    for (int kt = 0; kt < 4; ++kt) {
        const int kb = kt * 32 + (lane >> 4) * 8;
        f16x8 af3[4], bf3[2];
        #pragma unroll
        for (int i = 0; i < 4; ++i)
            af3[i] = *(const f16x8*)&Pn[(wm * 64 + i * 16 + (lane & 15)) * 136 + kb];
        #pragma unroll
        for (int j = 0; j < 2; ++j)
            bf3[j] = *(const f16x8*)&kvT[(wn * 32 + j * 16 + (lane & 15)) * 136 + kb];
        #pragma unroll
        for (int i = 0; i < 4; ++i)
            #pragma unroll
            for (int j = 0; j < 2; ++j)
                acc3[i][j] = __builtin_amdgcn_mfma_f32_16x16x32_f16(af3[i], bf3[j], acc3[i][j], 0, 0, 0);
    }

    f16* ob = ohA + ((size_t)(b * PN) + nt * 128) * PC + h * PD;
    #pragma unroll
    for (int i = 0; i < 4; ++i) {
        #pragma unroll
        for (int j = 0; j < 2; ++j) {
            const int d = wn * 32 + j * 16 + cc;
            #pragma unroll
            for (int r = 0; r < 4; ++r) {
                const int n = wm * 64 + i * 16 + quad * 4 + r;
                ob[(size_t)n * PC + d] = (f16)(acc3[i][j][r] / dns[n]);
            }
        }
    }
}

// ---------------- output projection GEMM: 8-wave (512t) occupancy variant ----------------
// Waves 4M x 2N, per-wave 32x32 output: acc[2][2]=16 AGPR. Same loop/swizzle.
__global__ __launch_bounds__(512) void gemm_proj(
        const f16* __restrict__ A,    // [8192][768]
        const f16* __restrict__ Bm,   // [768][768]
        float* __restrict__ Cm, const float* __restrict__ bias)
{
    __shared__ f16 As[128 * 64];
    __shared__ f16 Bs[64 * 64];
    const int t = threadIdx.x;
    const int wave = t >> 6, lane = t & 63;
    const int wm = wave >> 1, wn = wave & 1;     // 4M x 2N
    const int bi = blockIdx.x * 128, bj = blockIdx.y * 64;

    f32x4 acc[2][2] = {};

    const int rowi = lane >> 3;
    const int cb = (lane & 7) ^ ((lane >> 4) & 3);
    // B: each wave stages one 8-row slab (rows wave*8..wave*8+7). For odd
    // waves the slab base is ≡8 mod 16 -> swizzle key gets ^4.
    const int cbB = cb ^ ((wave & 1) << 2);
    const f16* ApE = A + (size_t)(bi + wave * 16 + rowi) * PC + cb * 8;
    const f16* ApO = A + (size_t)(bi + wave * 16 + rowi) * PC + (cb ^ 4) * 8;
    const f16* BpW = Bm + (size_t)(bj + wave * 8 + rowi) * PC + cbB * 8;
    f16* AsB = &As[wave * 16 * 64];
    f16* BsB = &Bs[wave * 8 * 64];

    const int q4 = lane >> 4;
    for (int kt = 0; kt < 12; ++kt) {
        const int k0 = kt * 64;
        __syncthreads();
        GLL(ApE + k0,                  AsB);
        GLL(ApO + k0 + (size_t)8 * PC, AsB + 8 * 64);
        GLL(BpW + k0,                  BsB);
        __syncthreads();

        #pragma unroll
        for (int kh = 0; kh < 2; ++kh) {
            f16x8 af[2], bf[2];
            #pragma unroll
            for (int i = 0; i < 2; ++i) {
                const int r = wm * 32 + i * 16 + (lane & 15);
                const int p = (kh * 4 + q4) ^ ((r >> 1) & 7);
                af[i] = *(const f16x8*)&As[r * 64 + p * 8];
            }
            #pragma unroll
            for (int j = 0; j < 2; ++j) {
                const int r = wn * 32 + j * 16 + (lane & 15);
                const int p = (kh * 4 + q4) ^ ((r >> 1) & 7);
                bf[j] = *(const f16x8*)&Bs[r * 64 + p * 8];
            }
            #pragma unroll
            for (int i = 0; i < 2; ++i)
                #pragma unroll
                for (int j = 0; j < 2; ++j)
                    acc[i][j] = __builtin_amdgcn_mfma_f32_16x16x32_f16(af[i], bf[j], acc[i][j], 0, 0, 0);
        }
    }

    const int cr = (lane >> 4) * 4, cc = lane & 15;
    #pragma unroll
    for (int i = 0; i < 2; ++i) {
        const int row = bi + wm * 32 + i * 16 + cr;
        #pragma unroll
        for (int j = 0; j < 2; ++j) {
            const int col = bj + wn * 32 + j * 16 + cc;
            const float bv = bias[col];
            #pragma unroll
            for (int r = 0; r < 4; ++r)
                Cm[(size_t)(row + r) * PC + col] = acc[i][j][r] + bv;
        }
    }
}

extern "C" void kernel_launch(void* const* d_in, const int* in_sizes, int n_in,
                              void* d_out, int out_size, void* d_ws, size_t ws_size,
                              hipStream_t stream) {
    const float* x      = (const float*)d_in[0];
    const float* qkv_w  = (const float*)d_in[1];
    const float* proj_w = (const float*)d_in[2];
    const float* proj_b = (const float*)d_in[3];
    const float* rm     = (const float*)d_in[4];
    float* out = (float*)d_out;

    char* ws = (char*)d_ws;
    f16*   Ax   = (f16*)(ws);                     // [8192][768]      = 12,582,912
    f16*   Bqk  = (f16*)(ws + 12582912);          // [2304][768]      =  3,538,944
    f16*   Bp   = (f16*)(ws + 16121856);          // [768][768]       =  1,179,648
    f16*   Rt   = (f16*)(ws + 17301504);          // [12][128][64]    =    196,608
    f16*   zq   = (f16*)(ws + 17498112);          // [96][1024][64]   = 12,582,912
    f16*   zk   = (f16*)(ws + 30081024);          // [96][1024][64]   = 12,582,912
    f16*   vh   = (f16*)(ws + 42663936);          // [96][1024][64]   = 12,582,912
    float* sqq  = (float*)(ws + 55246848);        // [96][1024] f32   =    393,216
    float* sqk  = (float*)(ws + 55640064);        // [96][1024] f32   =    393,216
    float* kvf  = (float*)(ws + 56033280);        // [96][128][64] f32=  3,145,728
    float* sf   = (float*)(ws + 59179008);        // [96][128] f32    =     49,152
    f16*   ohA  = (f16*)(ws + 59228160);          // [8192][768]      = 12,582,912

    // partial-kv buffers ALIAS dead regions (no extra workspace):
    //   kvpA (nt 0-3) -> Ax region (dead after gemm_qkv)
    //   kvpB (nt 4-7) -> ohA region (not live until feat_apply, after kv_reduce)
    //   sfp           -> Bqk region (dead after gemm_qkv)
    float* kvpA = (float*)(ws);                   // 4 * 96*128*64 f32 = 12,582,912
    float* kvpB = (float*)(ws + 59228160);        // 4 * 96*128*64 f32 = 12,582,912
    float* sfp  = (float*)(ws + 12582912);        // [8][96][128] f32  =    393,216

    // 1) conversions
    conv_all<<<11276, 192, 0, stream>>>(x, qkv_w, proj_w, rm, Ax, Bqk, Bp, Rt);

    // 2) fused qkv projection (8-wave occupancy variant)
    gemm_qkv<<<dim3(64, 18), 512, 0, stream>>>(Ax, Bqk, zq, zk, vh, sqq, sqk);

    // 3) fused feat(k) + kf^T@V + colsum -> per-nt partials (plain stores)
    feat_kv<<<dim3(8, 96), 256, 0, stream>>>(zk, Rt, sqk, vh, kvpA, kvpB, sfp);

    // 4) reduce partials -> kvf, sf
    kv_reduce<<<dim3(96, 9), 256, 0, stream>>>(kvpA, kvpB, sfp, kvf, sf);

    // 5) fused feat(q) + denom + P@KV -> ohA
    feat_apply<<<dim3(8, 96), 256, 0, stream>>>(zq, Rt, sqq, kvf, sf, ohA);

    // 6) out = oh @ proj_w^T + proj_b
    gemm_proj<<<dim3(64, 12), 512, 0, stream>>>(ohA, Bp, out, proj_b);
}

// Round 6
// 176.739 us; speedup vs baseline: 1.0177x; 1.0177x over previous
//
#include <hip/hip_runtime.h>
#include <hip/hip_bf16.h>

// Problem constants: B=8, N=1024, C=768, H=12, D=64, M=128
#define PB 8
#define PN 1024
#define PC 768
#define PH 12
#define PD 64
#define PM 128
#define SQ 0.35355339059327373f      // (D^-0.5)^0.5 = D^-0.25
#define MSCALE 0.08838834764831843f  // M^-0.5

typedef _Float16 f16;
typedef f16 f16x8 __attribute__((ext_vector_type(8)));
typedef f16 f16x4 __attribute__((ext_vector_type(4)));
typedef float f32x4 __attribute__((ext_vector_type(4)));

#define GLL(src, dst) __builtin_amdgcn_global_load_lds( \
    (const __attribute__((address_space(1))) void*)(src), \
    (__attribute__((address_space(3))) void*)(dst), 16, 0, 0)

// ---------------- conversions, one launch ----------------
// [0,8192): x; [8192,10496): qkv_w; [10496,11264): proj_w; [11264,11276): Rt
__global__ __launch_bounds__(192) void conv_all(
        const float* __restrict__ x, const float* __restrict__ qkv_w,
        const float* __restrict__ proj_w, const float* __restrict__ rm,
        f16* __restrict__ Ax, f16* __restrict__ Bqk, f16* __restrict__ Bp,
        f16* __restrict__ Rt)
{
    const int bid = blockIdx.x;
    const int t = threadIdx.x;
    if (bid < 11264) {
        const float* src; f16* dst; int r;
        if (bid < 8192)       { src = x;      dst = Ax;  r = bid; }
        else if (bid < 10496) { src = qkv_w;  dst = Bqk; r = bid - 8192; }
        else                  { src = proj_w; dst = Bp;  r = bid - 10496; }
        const int c = t * 4;
        float4 v = *(const float4*)&src[(size_t)r * PC + c];
        f16x4 hv;
        hv.x = (f16)v.x; hv.y = (f16)v.y; hv.z = (f16)v.z; hv.w = (f16)v.w;
        *(f16x4*)&dst[(size_t)r * PC + c] = hv;
    } else {
        const int h = bid - 11264;
        for (int e = t; e < PD * PM; e += 192)
            Rt[(size_t)h * 8192 + e] = (f16)rm[(size_t)h * 8192 + (e & 63) * PM + (e >> 6)];
    }
}

// ---------------- fused qkv GEMM: 64x128 tile, 256t/4 waves, max co-residency ----------------
// r5 evidence: occupancy is THE lever (VGPR 84->48 gave -18%). This shrinks
// the tile to 64x128 (LDS 24KB, ~48 VGPR) -> up to 6 blocks/CU resident and
// 2304-block grid (9 clean rounds on 256 CUs). Per-wave work per K-step is
// unchanged (32x64 output, 16 MFMA). Same verified swizzle + 2-barrier loop.
// B re-fetch doubles but B is 3.5MB (L2-resident); blocks sharing an A-row
// tile are 128 apart in linear ID -> same XCD.
__global__ __launch_bounds__(256) void gemm_qkv(
        const f16* __restrict__ A,    // [8192][768]
        const f16* __restrict__ Bm,   // [2304][768]
        f16* __restrict__ zq, f16* __restrict__ zk, f16* __restrict__ vh,
        float* __restrict__ sqq, float* __restrict__ sqk)
{
    __shared__ f16 As[64 * 64];
    __shared__ f16 Bs[128 * 64];
    const int t = threadIdx.x;
    const int wave = t >> 6, lane = t & 63;
    const int wm = wave >> 1, wn = wave & 1;     // 2M x 2N, wave owns 32x64
    const int bi = blockIdx.x * 64, bj = blockIdx.y * 128;

    f32x4 acc[2][4] = {};

    const int rowi = lane >> 3;
    const int cb = (lane & 7) ^ ((lane >> 4) & 3);
    // A: each wave stages 16 rows (2 GLL, 8 rows each; base mult of 16 -> keys cb / cb^4)
    const f16* ApE = A + (size_t)(bi + wave * 16 + rowi) * PC + cb * 8;
    const f16* ApO = A + (size_t)(bi + wave * 16 + rowi) * PC + (cb ^ 4) * 8;
    // B: each wave stages 32 rows (4 GLL; round-0 verified E/O/E/O pattern)
    const f16* BpE = Bm + (size_t)(bj + wave * 32 + rowi) * PC + cb * 8;
    const f16* BpO = Bm + (size_t)(bj + wave * 32 + rowi) * PC + (cb ^ 4) * 8;
    f16* AsB = &As[wave * 16 * 64];
    f16* BsB = &Bs[wave * 32 * 64];

    const int q4 = lane >> 4;
    for (int kt = 0; kt < 12; ++kt) {
        const int k0 = kt * 64;
        __syncthreads();
        GLL(ApE + k0,                   AsB);
        GLL(ApO + k0 + (size_t) 8 * PC, AsB + 8 * 64);
        GLL(BpE + k0,                   BsB);
        GLL(BpO + k0 + (size_t) 8 * PC, BsB + 8 * 64);
        GLL(BpE + k0 + (size_t)16 * PC, BsB + 16 * 64);
        GLL(BpO + k0 + (size_t)24 * PC, BsB + 24 * 64);
        __syncthreads();

        #pragma unroll
        for (int kh = 0; kh < 2; ++kh) {
            f16x8 af[2], bf[4];
            #pragma unroll
            for (int i = 0; i < 2; ++i) {
                const int r = wm * 32 + i * 16 + (lane & 15);
                const int p = (kh * 4 + q4) ^ ((r >> 1) & 7);
                af[i] = *(const f16x8*)&As[r * 64 + p * 8];
            }
            #pragma unroll
            for (int j = 0; j < 4; ++j) {
                const int r = wn * 64 + j * 16 + (lane & 15);
                const int p = (kh * 4 + q4) ^ ((r >> 1) & 7);
                bf[j] = *(const f16x8*)&Bs[r * 64 + p * 8];
            }
            #pragma unroll
            for (int i = 0; i < 2; ++i)
                #pragma unroll
                for (int j = 0; j < 4; ++j)
                    acc[i][j] = __builtin_amdgcn_mfma_f32_16x16x32_f16(af[i], bf[j], acc[i][j], 0, 0, 0);
        }
    }

    // epilogue: identical mapping (per-wave rows=32 via i<2, cols=64 full head)
    const int quad = lane >> 4, cc = lane & 15;
    const int colbase = bj + wn * 64;
    const int b = bi >> 10;
    if (colbase < 1536) {
        const int which = colbase >= 768;
        const int h = (colbase - which * 768) >> 6;
        f16* zdst = which ? zk : zq;
        float* sdst = which ? sqk : sqq;
        const size_t bh = (size_t)(b * PH + h);
        #pragma unroll
        for (int i = 0; i < 2; ++i) {
            const int row0 = bi + wm * 32 + i * 16 + quad * 4;
            #pragma unroll
            for (int r = 0; r < 4; ++r) {
                const int n = (row0 + r) & 1023;
                f16 zh[4]; float psq = 0.f;
                #pragma unroll
                for (int j = 0; j < 4; ++j) {
                    zh[j] = (f16)(acc[i][j][r] * SQ);
                    float zf = (float)zh[j];
                    psq += zf * zf;
                }
                psq += __shfl_xor(psq, 1, 64);
                psq += __shfl_xor(psq, 2, 64);
                psq += __shfl_xor(psq, 4, 64);
                psq += __shfl_xor(psq, 8, 64);
                if (cc == 0) sdst[(bh << 10) + n] = 0.5f * psq;
                f16* zp = zdst + (((bh << 10) + n) << 6);
                #pragma unroll
                for (int j = 0; j < 4; ++j) zp[j * 16 + cc] = zh[j];
            }
        }
    } else {
        const int h = (colbase - 1536) >> 6;
        const size_t bh = (size_t)(b * PH + h);
        #pragma unroll
        for (int i = 0; i < 2; ++i) {
            const int row0 = bi + wm * 32 + i * 16 + quad * 4;
            #pragma unroll
            for (int r = 0; r < 4; ++r) {
                const int n = (row0 + r) & 1023;
                f16* vp = vh + (((bh << 10) + n) << 6);
                #pragma unroll
                for (int j = 0; j < 4; ++j) vp[j * 16 + cc] = (f16)acc[i][j][r];
            }
        }
    }
}

// ---------------- fused feat(k) + kf^T@V partial + colsum -> per-nt partials (NO atomics) ----------------
__global__ __launch_bounds__(256) void feat_kv(
        const f16* __restrict__ zk, const f16* __restrict__ Rt,
        const float* __restrict__ sqk, const f16* __restrict__ vh,
        float* __restrict__ kvpA, float* __restrict__ kvpB, float* __restrict__ sfp)
{
    __shared__ __align__(16) char smem[52224];
    f16* As = (f16*)smem;              // stage z [128][64] (16KB)
    f16* Bs = (f16*)(smem + 16384);    // stage Rt [128][64] (16KB)
    f16* Pt = (f16*)smem;              // [128 m][136 n] aliases stages
    f16* vT = (f16*)(smem + 34816);    // [64 d][136 n]
    __shared__ float sqs[128];

    const int t = threadIdx.x;
    const int wave = t >> 6, lane = t & 63;
    const int wm = wave >> 1, wn = wave & 1;
    const int nt = blockIdx.x, bh = blockIdx.y;
    const int h = bh % PH;

    const f16* A = zk + (((size_t)bh << 10) + nt * 128) * 64;
    const f16* Bm = Rt + (size_t)h * (PM * PD);

    if (t < 128) sqs[t] = sqk[((size_t)bh << 10) + nt * 128 + t];

    const int rowi = lane >> 3;
    const int cb = (lane & 7) ^ ((lane >> 4) & 3);
    const f16* ApE = A + (size_t)(wave * 32 + rowi) * 64 + cb * 8;
    const f16* ApO = A + (size_t)(wave * 32 + rowi) * 64 + (cb ^ 4) * 8;
    const f16* BpE = Bm + (size_t)(wave * 32 + rowi) * 64 + cb * 8;
    const f16* BpO = Bm + (size_t)(wave * 32 + rowi) * 64 + (cb ^ 4) * 8;
    f16* AsB = &As[wave * 32 * 64];
    f16* BsB = &Bs[wave * 32 * 64];
    GLL(ApE,            AsB);
    GLL(ApO + 8 * 64,   AsB + 8 * 64);
    GLL(ApE + 16 * 64,  AsB + 16 * 64);
    GLL(ApO + 24 * 64,  AsB + 24 * 64);
    GLL(BpE,            BsB);
    GLL(BpO + 8 * 64,   BsB + 8 * 64);
    GLL(BpE + 16 * 64,  BsB + 16 * 64);
    GLL(BpO + 24 * 64,  BsB + 24 * 64);
    __syncthreads();

    const int q4 = lane >> 4;
    f32x4 acc[4][4] = {};
    #pragma unroll
    for (int kh = 0; kh < 2; ++kh) {
        f16x8 af[4], bf[4];
        #pragma unroll
        for (int i = 0; i < 4; ++i) {
            const int r = wm * 64 + i * 16 + (lane & 15);
            const int p = (kh * 4 + q4) ^ ((r >> 1) & 7);
            af[i] = *(const f16x8*)&As[r * 64 + p * 8];
        }
        #pragma unroll
        for (int j = 0; j < 4; ++j) {
            const int r = wn * 64 + j * 16 + (lane & 15);
            const int p = (kh * 4 + q4) ^ ((r >> 1) & 7);
            bf[j] = *(const f16x8*)&Bs[r * 64 + p * 8];
        }
        #pragma unroll
        for (int i = 0; i < 4; ++i)
            #pragma unroll
            for (int j = 0; j < 4; ++j)
                acc[i][j] = __builtin_amdgcn_mfma_f32_16x16x32_f16(af[i], bf[j], acc[i][j], 0, 0, 0);
    }

    const int quad = lane >> 4, cc = lane & 15;
    __syncthreads();

    #pragma unroll
    for (int i = 0; i < 4; ++i) {
        #pragma unroll
        for (int j = 0; j < 4; ++j) {
            const int col = wn * 64 + j * 16 + cc;
            #pragma unroll
            for (int r = 0; r < 4; ++r) {
                const int rl = wm * 64 + i * 16 + quad * 4 + r;
                Pt[col * 136 + rl] = (f16)(__expf(acc[i][j][r] - sqs[rl]) * MSCALE);
            }
        }
    }
    {
        const int vn = t >> 1;
        const int vhf = (t & 1) * 32;
        const f16* vbase = vh + (((size_t)bh << 10) + nt * 128 + vn) * 64 + vhf;
        #pragma unroll
        for (int k = 0; k < 4; ++k) {
            f16x8 vv = *(const f16x8*)&vbase[k * 8];
            #pragma unroll
            for (int e = 0; e < 8; ++e)
                vT[(vhf + k * 8 + e) * 136 + vn] = vv[e];
        }
    }
    __syncthreads();

    f32x4 acc2[4][2] = {};
    #pragma unroll
    for (int kt = 0; kt < 4; ++kt) {
        const int kb = kt * 32 + (lane >> 4) * 8;
        f16x8 af2[4], bf2[2];
        #pragma unroll
        for (int i = 0; i < 4; ++i)
            af2[i] = *(const f16x8*)&Pt[(wm * 64 + i * 16 + (lane & 15)) * 136 + kb];
        #pragma unroll
        for (int j = 0; j < 2; ++j)
            bf2[j] = *(const f16x8*)&vT[(wn * 32 + j * 16 + (lane & 15)) * 136 + kb];
        #pragma unroll
        for (int i = 0; i < 4; ++i)
            #pragma unroll
            for (int j = 0; j < 2; ++j)
                acc2[i][j] = __builtin_amdgcn_mfma_f32_16x16x32_f16(af2[i], bf2[j], acc2[i][j], 0, 0, 0);
    }

    // plain stores to this nt's partial buffer (each element written exactly once per block)
    float* kvo = ((nt < 4) ? (kvpA + (size_t)nt * 786432)
                           : (kvpB + (size_t)(nt - 4) * 786432)) + (size_t)bh * 8192;
    #pragma unroll
    for (int i = 0; i < 4; ++i) {
        #pragma unroll
        for (int j = 0; j < 2; ++j) {
            const int d = wn * 32 + j * 16 + cc;
            #pragma unroll
            for (int r = 0; r < 4; ++r) {
                const int m = wm * 64 + i * 16 + quad * 4 + r;
                kvo[m * 64 + d] = acc2[i][j][r];
            }
        }
    }
    {
        const int sm = t >> 1, shf = (t & 1) * 64;
        float sp = 0.f;
        #pragma unroll
        for (int k = 0; k < 8; ++k) {
            f16x8 pv = *(const f16x8*)&Pt[sm * 136 + shf + k * 8];
            #pragma unroll
            for (int e = 0; e < 8; ++e) sp += (float)pv[e];
        }
        sp += __shfl_xor(sp, 1, 64);
        if ((t & 1) == 0) sfp[((size_t)nt * 96 + bh) * 128 + sm] = sp;
    }
}

// ---------------- reduce the 8 per-nt partials -> kvf, sf (BW-bound, ~28 MB) ----------------
__global__ __launch_bounds__(256) void kv_reduce(
        const float* __restrict__ kvpA, const float* __restrict__ kvpB,
        const float* __restrict__ sfp, float* __restrict__ kvf, float* __restrict__ sf)
{
    const int bh = blockIdx.x;
    if (blockIdx.y == 8) {
        const int t = threadIdx.x;
        if (t < 128) {
            float s = 0.f;
            #pragma unroll
            for (int nt = 0; nt < 8; ++nt)
                s += sfp[((size_t)nt * 96 + bh) * 128 + t];
            sf[(size_t)bh * 128 + t] = s;
        }
        return;
    }
    const size_t base = (size_t)bh * 8192 + blockIdx.y * 1024 + threadIdx.x * 4;
    float4 s = *(const float4*)&kvpA[base];
    #pragma unroll
    for (int nt = 1; nt < 4; ++nt) {
        float4 v = *(const float4*)&kvpA[(size_t)nt * 786432 + base];
        s.x += v.x; s.y += v.y; s.z += v.z; s.w += v.w;
    }
    #pragma unroll
    for (int nt = 0; nt < 4; ++nt) {
        float4 v = *(const float4*)&kvpB[(size_t)nt * 786432 + base];
        s.x += v.x; s.y += v.y; s.z += v.z; s.w += v.w;
    }
    *(float4*)&kvf[base] = s;
}

// ---------------- fused feat(q) + denom + P@KV + divide (BK=64, 1 stage) ----------------
__global__ __launch_bounds__(256) void feat_apply(
        const f16* __restrict__ zq, const f16* __restrict__ Rt,
        const float* __restrict__ sqq, const float* __restrict__ kvf,
        const float* __restrict__ sf, f16* __restrict__ ohA)
{
    __shared__ __align__(16) char smem[52224];
    f16* As = (f16*)smem;
    f16* Bs = (f16*)(smem + 16384);
    f16* Pn = (f16*)smem;              // [128 n][136 m]
    f16* kvT = (f16*)(smem + 34816);   // [64 d][136 m]
    __shared__ float sqs[128], ssm[128], dns[128];

    const int t = threadIdx.x;
    const int wave = t >> 6, lane = t & 63;
    const int wm = wave >> 1, wn = wave & 1;
    const int nt = blockIdx.x, bh = blockIdx.y;
    const int b = bh / PH, h = bh % PH;

    const f16* A = zq + (((size_t)bh << 10) + nt * 128) * 64;
    const f16* Bm = Rt + (size_t)h * (PM * PD);

    if (t < 128) {
        sqs[t] = sqq[((size_t)bh << 10) + nt * 128 + t];
        ssm[t] = sf[(size_t)bh * 128 + t];
    }

    const int rowi = lane >> 3;
    const int cb = (lane & 7) ^ ((lane >> 4) & 3);
    const f16* ApE = A + (size_t)(wave * 32 + rowi) * 64 + cb * 8;
    const f16* ApO = A + (size_t)(wave * 32 + rowi) * 64 + (cb ^ 4) * 8;
    const f16* BpE = Bm + (size_t)(wave * 32 + rowi) * 64 + cb * 8;
    const f16* BpO = Bm + (size_t)(wave * 32 + rowi) * 64 + (cb ^ 4) * 8;
    f16* AsB = &As[wave * 32 * 64];
    f16* BsB = &Bs[wave * 32 * 64];
    GLL(ApE,            AsB);
    GLL(ApO + 8 * 64,   AsB + 8 * 64);
    GLL(ApE + 16 * 64,  AsB + 16 * 64);
    GLL(ApO + 24 * 64,  AsB + 24 * 64);
    GLL(BpE,            BsB);
    GLL(BpO + 8 * 64,   BsB + 8 * 64);
    GLL(BpE + 16 * 64,  BsB + 16 * 64);
    GLL(BpO + 24 * 64,  BsB + 24 * 64);
    __syncthreads();

    const int q4 = lane >> 4;
    f32x4 acc[4][4] = {};
    #pragma unroll
    for (int kh = 0; kh < 2; ++kh) {
        f16x8 af[4], bf[4];
        #pragma unroll
        for (int i = 0; i < 4; ++i) {
            const int r = wm * 64 + i * 16 + (lane & 15);
            const int p = (kh * 4 + q4) ^ ((r >> 1) & 7);
            af[i] = *(const f16x8*)&As[r * 64 + p * 8];
        }
        #pragma unroll
        for (int j = 0; j < 4; ++j) {
            const int r = wn * 64 + j * 16 + (lane & 15);
            const int p = (kh * 4 + q4) ^ ((r >> 1) & 7);
            bf[j] = *(const f16x8*)&Bs[r * 64 + p * 8];
        }
        #pragma unroll
        for (int i = 0; i < 4; ++i)
            #pragma unroll
            for (int j = 0; j < 4; ++j)
                acc[i][j] = __builtin_amdgcn_mfma_f32_16x16x32_f16(af[i], bf[j], acc[i][j], 0, 0, 0);
    }

    const int quad = lane >> 4, cc = lane & 15;
    __syncthreads();

    #pragma unroll
    for (int i = 0; i < 4; ++i) {
        #pragma unroll
        for (int j = 0; j < 4; ++j) {
            const int col = wn * 64 + j * 16 + cc;
            #pragma unroll
            for (int r = 0; r < 4; ++r) {
                const int rl = wm * 64 + i * 16 + quad * 4 + r;
                Pn[rl * 136 + col] = (f16)(__expf(acc[i][j][r] - sqs[rl]) * MSCALE);
            }
        }
    }
    {
        const int m = t >> 1;
        const int dh2 = (t & 1) * 32;
        const float* kvb = kvf + ((size_t)bh * 128 + m) * 64 + dh2;
        #pragma unroll
        for (int k = 0; k < 8; ++k) {
            float4 k4 = *(const float4*)&kvb[k * 4];
            kvT[(dh2 + k * 4 + 0) * 136 + m] = (f16)k4.x;
            kvT[(dh2 + k * 4 + 1) * 136 + m] = (f16)k4.y;
            kvT[(dh2 + k * 4 + 2) * 136 + m] = (f16)k4.z;
            kvT[(dh2 + k * 4 + 3) * 136 + m] = (f16)k4.w;
        }
    }
    __syncthreads();

    {
        const int n = t >> 1, mh = (t & 1) * 64;
        float p = 0.f;
        #pragma unroll
        for (int k = 0; k < 8; ++k) {
            f16x8 pv = *(const f16x8*)&Pn[n * 136 + mh + k * 8];
            #pragma unroll
            for (int e = 0; e < 8; ++e)
                p += (float)pv[e] * ssm[mh + k * 8 + e];
        }
        p += __shfl_xor(p, 1, 64);
        if ((t & 1) == 0) dns[n] = (p < 1e-12f) ? 1e-12f : p;
    }
    __syncthreads();

    f32x4 acc3[4][2] = {};
    #pragma unroll
    for (int kt = 0; kt < 4; ++kt) {
        const int kb = kt * 32 + (lane >> 4) * 8;
        f16x8 af3[4], bf3[2];
        #pragma unroll
        for (int i = 0; i < 4; ++i)
            af3[i] = *(const f16x8*)&Pn[(wm * 64 + i * 16 + (lane & 15)) * 136 + kb];
        #pragma unroll
        for (int j = 0; j < 2; ++j)
            bf3[j] = *(const f16x8*)&kvT[(wn * 32 + j * 16 + (lane & 15)) * 136 + kb];
        #pragma unroll
        for (int i = 0; i < 4; ++i)
            #pragma unroll
            for (int j = 0; j < 2; ++j)
                acc3[i][j] = __builtin_amdgcn_mfma_f32_16x16x32_f16(af3[i], bf3[j], acc3[i][j], 0, 0, 0);
    }

    f16* ob = ohA + ((size_t)(b * PN) + nt * 128) * PC + h * PD;
    #pragma unroll
    for (int i = 0; i < 4; ++i) {
        #pragma unroll
        for (int j = 0; j < 2; ++j) {
            const int d = wn * 32 + j * 16 + cc;
            #pragma unroll
            for (int r = 0; r < 4; ++r) {
                const int n = wm * 64 + i * 16 + quad * 4 + r;
                ob[(size_t)n * PC + d] = (f16)(acc3[i][j][r] / dns[n]);
            }
        }
    }
}

// ---------------- output projection GEMM (BK=64, BN=64): round-0 proven 4-wave ----------------
// r5 measured: 8-wave 32x32-per-wave variant regressed ~10us. Keep 4-wave.
__global__ __launch_bounds__(256) void gemm_proj(
        const f16* __restrict__ A,    // [8192][768]
        const f16* __restrict__ Bm,   // [768][768]
        float* __restrict__ Cm, const float* __restrict__ bias)
{
    __shared__ f16 As[128 * 64];
    __shared__ f16 Bs[64 * 64];
    const int t = threadIdx.x;
    const int wave = t >> 6, lane = t & 63;
    const int wm = wave >> 1, wn = wave & 1;
    const int bi = blockIdx.x * 128, bj = blockIdx.y * 64;

    f32x4 acc[4][2] = {};

    const int rowi = lane >> 3;
    const int cb = (lane & 7) ^ ((lane >> 4) & 3);
    const f16* ApE = A + (size_t)(bi + wave * 32 + rowi) * PC + cb * 8;
    const f16* ApO = A + (size_t)(bi + wave * 32 + rowi) * PC + (cb ^ 4) * 8;
    const f16* BpE = Bm + (size_t)(bj + wave * 16 + rowi) * PC + cb * 8;
    const f16* BpO = Bm + (size_t)(bj + wave * 16 + rowi) * PC + (cb ^ 4) * 8;
    f16* AsB = &As[wave * 32 * 64];
    f16* BsB = &Bs[wave * 16 * 64];

    const int q4 = lane >> 4;
    for (int kt = 0; kt < 12; ++kt) {
        const int k0 = kt * 64;
        __syncthreads();
        GLL(ApE + k0,               AsB);
        GLL(ApO + k0 + (size_t) 8 * PC, AsB + 8 * 64);
        GLL(ApE + k0 + (size_t)16 * PC, AsB + 16 * 64);
        GLL(ApO + k0 + (size_t)24 * PC, AsB + 24 * 64);
        GLL(BpE + k0,               BsB);
        GLL(BpO + k0 + (size_t) 8 * PC, BsB + 8 * 64);
        __syncthreads();

        #pragma unroll
        for (int kh = 0; kh < 2; ++kh) {
            f16x8 af[4], bf[2];
            #pragma unroll
            for (int i = 0; i < 4; ++i) {
                const int r = wm * 64 + i * 16 + (lane & 15);
                const int p = (kh * 4 + q4) ^ ((r >> 1) & 7);
                af[i] = *(const f16x8*)&As[r * 64 + p * 8];
            }
            #pragma unroll
            for (int j = 0; j < 2; ++j) {
                const int r = wn * 32 + j * 16 + (lane & 15);
                const int p = (kh * 4 + q4) ^ ((r >> 1) & 7);
                bf[j] = *(const f16x8*)&Bs[r * 64 + p * 8];
            }
            #pragma unroll
            for (int i = 0; i < 4; ++i)
                #pragma unroll
                for (int j = 0; j < 2; ++j)
                    acc[i][j] = __builtin_amdgcn_mfma_f32_16x16x32_f16(af[i], bf[j], acc[i][j], 0, 0, 0);
        }
    }

    const int cr = (lane >> 4) * 4, cc = lane & 15;
    #pragma unroll
    for (int i = 0; i < 4; ++i) {
        const int row = bi + wm * 64 + i * 16 + cr;
        #pragma unroll
        for (int j = 0; j < 2; ++j) {
            const int col = bj + wn * 32 + j * 16 + cc;
            const float bv = bias[col];
            #pragma unroll
            for (int r = 0; r < 4; ++r)
                Cm[(size_t)(row + r) * PC + col] = acc[i][j][r] + bv;
        }
    }
}

extern "C" void kernel_launch(void* const* d_in, const int* in_sizes, int n_in,
                              void* d_out, int out_size, void* d_ws, size_t ws_size,
                              hipStream_t stream) {
    const float* x      = (const float*)d_in[0];
    const float* qkv_w  = (const float*)d_in[1];
    const float* proj_w = (const float*)d_in[2];
    const float* proj_b = (const float*)d_in[3];
    const float* rm     = (const float*)d_in[4];
    float* out = (float*)d_out;

    char* ws = (char*)d_ws;
    f16*   Ax   = (f16*)(ws);                     // [8192][768]      = 12,582,912
    f16*   Bqk  = (f16*)(ws + 12582912);          // [2304][768]      =  3,538,944
    f16*   Bp   = (f16*)(ws + 16121856);          // [768][768]       =  1,179,648
    f16*   Rt   = (f16*)(ws + 17301504);          // [12][128][64]    =    196,608
    f16*   zq   = (f16*)(ws + 17498112);          // [96][1024][64]   = 12,582,912
    f16*   zk   = (f16*)(ws + 30081024);          // [96][1024][64]   = 12,582,912
    f16*   vh   = (f16*)(ws + 42663936);          // [96][1024][64]   = 12,582,912
    float* sqq  = (float*)(ws + 55246848);        // [96][1024] f32   =    393,216
    float* sqk  = (float*)(ws + 55640064);        // [96][1024] f32   =    393,216
    float* kvf  = (float*)(ws + 56033280);        // [96][128][64] f32=  3,145,728
    float* sf   = (float*)(ws + 59179008);        // [96][128] f32    =     49,152
    f16*   ohA  = (f16*)(ws + 59228160);          // [8192][768]      = 12,582,912

    // partial-kv buffers ALIAS dead regions (no extra workspace):
    //   kvpA (nt 0-3) -> Ax region (dead after gemm_qkv)
    //   kvpB (nt 4-7) -> ohA region (not live until feat_apply, after kv_reduce)
    //   sfp           -> Bqk region (dead after gemm_qkv)
    float* kvpA = (float*)(ws);                   // 4 * 96*128*64 f32 = 12,582,912
    float* kvpB = (float*)(ws + 59228160);        // 4 * 96*128*64 f32 = 12,582,912
    float* sfp  = (float*)(ws + 12582912);        // [8][96][128] f32  =    393,216

    // 1) conversions
    conv_all<<<11276, 192, 0, stream>>>(x, qkv_w, proj_w, rm, Ax, Bqk, Bp, Rt);

    // 2) fused qkv projection (64x128 tile, 256t, max co-residency)
    gemm_qkv<<<dim3(128, 18), 256, 0, stream>>>(Ax, Bqk, zq, zk, vh, sqq, sqk);

    // 3) fused feat(k) + kf^T@V + colsum -> per-nt partials (plain stores)
    feat_kv<<<dim3(8, 96), 256, 0, stream>>>(zk, Rt, sqk, vh, kvpA, kvpB, sfp);

    // 4) reduce partials -> kvf, sf
    kv_reduce<<<dim3(96, 9), 256, 0, stream>>>(kvpA, kvpB, sfp, kvf, sf);

    // 5) fused feat(q) + denom + P@KV -> ohA
    feat_apply<<<dim3(8, 96), 256, 0, stream>>>(zq, Rt, sqq, kvf, sf, ohA);

    // 6) out = oh @ proj_w^T + proj_b
    gemm_proj<<<dim3(64, 12), 256, 0, stream>>>(ohA, Bp, out, proj_b);
}

// Round 7
// 172.491 us; speedup vs baseline: 1.0428x; 1.0246x over previous
//
#include <hip/hip_runtime.h>
#include <hip/hip_bf16.h>

// Problem constants: B=8, N=1024, C=768, H=12, D=64, M=128
#define PB 8
#define PN 1024
#define PC 768
#define PH 12
#define PD 64
#define PM 128
#define SQ 0.35355339059327373f      // (D^-0.5)^0.5 = D^-0.25
#define MSCALE 0.08838834764831843f  // M^-0.5

typedef _Float16 f16;
typedef f16 f16x8 __attribute__((ext_vector_type(8)));
typedef f16 f16x4 __attribute__((ext_vector_type(4)));
typedef float f32x4 __attribute__((ext_vector_type(4)));

#define GLL(src, dst) __builtin_amdgcn_global_load_lds( \
    (const __attribute__((address_space(1))) void*)(src), \
    (__attribute__((address_space(3))) void*)(dst), 16, 0, 0)

// ---------------- conversions, one launch ----------------
// [0,8192): x; [8192,10496): qkv_w; [10496,11264): proj_w; [11264,11276): Rt
__global__ __launch_bounds__(192) void conv_all(
        const float* __restrict__ x, const float* __restrict__ qkv_w,
        const float* __restrict__ proj_w, const float* __restrict__ rm,
        f16* __restrict__ Ax, f16* __restrict__ Bqk, f16* __restrict__ Bp,
        f16* __restrict__ Rt)
{
    const int bid = blockIdx.x;
    const int t = threadIdx.x;
    if (bid < 11264) {
        const float* src; f16* dst; int r;
        if (bid < 8192)       { src = x;      dst = Ax;  r = bid; }
        else if (bid < 10496) { src = qkv_w;  dst = Bqk; r = bid - 8192; }
        else                  { src = proj_w; dst = Bp;  r = bid - 10496; }
        const int c = t * 4;
        float4 v = *(const float4*)&src[(size_t)r * PC + c];
        f16x4 hv;
        hv.x = (f16)v.x; hv.y = (f16)v.y; hv.z = (f16)v.z; hv.w = (f16)v.w;
        *(f16x4*)&dst[(size_t)r * PC + c] = hv;
    } else {
        const int h = bid - 11264;
        for (int e = t; e < PD * PM; e += 192)
            Rt[(size_t)h * 8192 + e] = (f16)rm[(size_t)h * 8192 + (e & 63) * PM + (e >> 6)];
    }
}

// ---------------- fused qkv GEMM: 64x128 tile, 256t/4 waves (r6 proven, 42us) ----------------
// Occupancy ladder measured in-session: 128^2/4w 84VGPR = 56us ->
// 128^2/8w 48VGPR = 46us -> 64x128/4w 48VGPR 24KB LDS = 42us. Keep.
__global__ __launch_bounds__(256) void gemm_qkv(
        const f16* __restrict__ A,    // [8192][768]
        const f16* __restrict__ Bm,   // [2304][768]
        f16* __restrict__ zq, f16* __restrict__ zk, f16* __restrict__ vh,
        float* __restrict__ sqq, float* __restrict__ sqk)
{
    __shared__ f16 As[64 * 64];
    __shared__ f16 Bs[128 * 64];
    const int t = threadIdx.x;
    const int wave = t >> 6, lane = t & 63;
    const int wm = wave >> 1, wn = wave & 1;     // 2M x 2N, wave owns 32x64
    const int bi = blockIdx.x * 64, bj = blockIdx.y * 128;

    f32x4 acc[2][4] = {};

    const int rowi = lane >> 3;
    const int cb = (lane & 7) ^ ((lane >> 4) & 3);
    const f16* ApE = A + (size_t)(bi + wave * 16 + rowi) * PC + cb * 8;
    const f16* ApO = A + (size_t)(bi + wave * 16 + rowi) * PC + (cb ^ 4) * 8;
    const f16* BpE = Bm + (size_t)(bj + wave * 32 + rowi) * PC + cb * 8;
    const f16* BpO = Bm + (size_t)(bj + wave * 32 + rowi) * PC + (cb ^ 4) * 8;
    f16* AsB = &As[wave * 16 * 64];
    f16* BsB = &Bs[wave * 32 * 64];

    const int q4 = lane >> 4;
    for (int kt = 0; kt < 12; ++kt) {
        const int k0 = kt * 64;
        __syncthreads();
        GLL(ApE + k0,                   AsB);
        GLL(ApO + k0 + (size_t) 8 * PC, AsB + 8 * 64);
        GLL(BpE + k0,                   BsB);
        GLL(BpO + k0 + (size_t) 8 * PC, BsB + 8 * 64);
        GLL(BpE + k0 + (size_t)16 * PC, BsB + 16 * 64);
        GLL(BpO + k0 + (size_t)24 * PC, BsB + 24 * 64);
        __syncthreads();

        #pragma unroll
        for (int kh = 0; kh < 2; ++kh) {
            f16x8 af[2], bf[4];
            #pragma unroll
            for (int i = 0; i < 2; ++i) {
                const int r = wm * 32 + i * 16 + (lane & 15);
                const int p = (kh * 4 + q4) ^ ((r >> 1) & 7);
                af[i] = *(const f16x8*)&As[r * 64 + p * 8];
            }
            #pragma unroll
            for (int j = 0; j < 4; ++j) {
                const int r = wn * 64 + j * 16 + (lane & 15);
                const int p = (kh * 4 + q4) ^ ((r >> 1) & 7);
                bf[j] = *(const f16x8*)&Bs[r * 64 + p * 8];
            }
            #pragma unroll
            for (int i = 0; i < 2; ++i)
                #pragma unroll
                for (int j = 0; j < 4; ++j)
                    acc[i][j] = __builtin_amdgcn_mfma_f32_16x16x32_f16(af[i], bf[j], acc[i][j], 0, 0, 0);
        }
    }

    const int quad = lane >> 4, cc = lane & 15;
    const int colbase = bj + wn * 64;
    const int b = bi >> 10;
    if (colbase < 1536) {
        const int which = colbase >= 768;
        const int h = (colbase - which * 768) >> 6;
        f16* zdst = which ? zk : zq;
        float* sdst = which ? sqk : sqq;
        const size_t bh = (size_t)(b * PH + h);
        #pragma unroll
        for (int i = 0; i < 2; ++i) {
            const int row0 = bi + wm * 32 + i * 16 + quad * 4;
            #pragma unroll
            for (int r = 0; r < 4; ++r) {
                const int n = (row0 + r) & 1023;
                f16 zh[4]; float psq = 0.f;
                #pragma unroll
                for (int j = 0; j < 4; ++j) {
                    zh[j] = (f16)(acc[i][j][r] * SQ);
                    float zf = (float)zh[j];
                    psq += zf * zf;
                }
                psq += __shfl_xor(psq, 1, 64);
                psq += __shfl_xor(psq, 2, 64);
                psq += __shfl_xor(psq, 4, 64);
                psq += __shfl_xor(psq, 8, 64);
                if (cc == 0) sdst[(bh << 10) + n] = 0.5f * psq;
                f16* zp = zdst + (((bh << 10) + n) << 6);
                #pragma unroll
                for (int j = 0; j < 4; ++j) zp[j * 16 + cc] = zh[j];
            }
        }
    } else {
        const int h = (colbase - 1536) >> 6;
        const size_t bh = (size_t)(b * PH + h);
        #pragma unroll
        for (int i = 0; i < 2; ++i) {
            const int row0 = bi + wm * 32 + i * 16 + quad * 4;
            #pragma unroll
            for (int r = 0; r < 4; ++r) {
                const int n = (row0 + r) & 1023;
                f16* vp = vh + (((bh << 10) + n) << 6);
                #pragma unroll
                for (int j = 0; j < 4; ++j) vp[j * 16 + cc] = (f16)acc[i][j][r];
            }
        }
    }
}

// ---------------- fused feat(k): 8-wave (512t) occupancy variant ----------------
// r5/r6 mechanism applied here: same tile, same LDS (3 blocks/CU), but 24
// waves/CU instead of 12. Per-wave: MFMA1 acc[2][4] (32x64 of P),
// MFMA2 acc2[2][2] (32m x 32d of kvf).
__global__ __launch_bounds__(512) void feat_kv(
        const f16* __restrict__ zk, const f16* __restrict__ Rt,
        const float* __restrict__ sqk, const f16* __restrict__ vh,
        float* __restrict__ kvpA, float* __restrict__ kvpB, float* __restrict__ sfp)
{
    __shared__ __align__(16) char smem[52224];
    f16* As = (f16*)smem;              // stage z [128][64] (16KB)
    f16* Bs = (f16*)(smem + 16384);    // stage Rt [128][64] (16KB)
    f16* Pt = (f16*)smem;              // [128 m][136 n] aliases stages
    f16* vT = (f16*)(smem + 34816);    // [64 d][136 n]
    __shared__ float sqs[128];

    const int t = threadIdx.x;
    const int wave = t >> 6, lane = t & 63;
    const int wm = wave >> 1, wn = wave & 1;   // 4M(32-row) x 2N(64-col)
    const int nt = blockIdx.x, bh = blockIdx.y;
    const int h = bh % PH;

    const f16* A = zk + (((size_t)bh << 10) + nt * 128) * 64;
    const f16* Bm = Rt + (size_t)h * (PM * PD);

    if (t < 128) sqs[t] = sqk[((size_t)bh << 10) + nt * 128 + t];

    // staging: each of 8 waves stages a 16-row slab of z and Rt (2 GLL each)
    const int rowi = lane >> 3;
    const int cb = (lane & 7) ^ ((lane >> 4) & 3);
    const f16* ApE = A + (size_t)(wave * 16 + rowi) * 64 + cb * 8;
    const f16* ApO = A + (size_t)(wave * 16 + rowi) * 64 + (cb ^ 4) * 8;
    const f16* BpE = Bm + (size_t)(wave * 16 + rowi) * 64 + cb * 8;
    const f16* BpO = Bm + (size_t)(wave * 16 + rowi) * 64 + (cb ^ 4) * 8;
    f16* AsB = &As[wave * 16 * 64];
    f16* BsB = &Bs[wave * 16 * 64];
    GLL(ApE,           AsB);
    GLL(ApO + 8 * 64,  AsB + 8 * 64);
    GLL(BpE,           BsB);
    GLL(BpO + 8 * 64,  BsB + 8 * 64);
    __syncthreads();

    const int q4 = lane >> 4;
    f32x4 acc[2][4] = {};
    #pragma unroll
    for (int kh = 0; kh < 2; ++kh) {
        f16x8 af[2], bf[4];
        #pragma unroll
        for (int i = 0; i < 2; ++i) {
            const int r = wm * 32 + i * 16 + (lane & 15);
            const int p = (kh * 4 + q4) ^ ((r >> 1) & 7);
            af[i] = *(const f16x8*)&As[r * 64 + p * 8];
        }
        #pragma unroll
        for (int j = 0; j < 4; ++j) {
            const int r = wn * 64 + j * 16 + (lane & 15);
            const int p = (kh * 4 + q4) ^ ((r >> 1) & 7);
            bf[j] = *(const f16x8*)&Bs[r * 64 + p * 8];
        }
        #pragma unroll
        for (int i = 0; i < 2; ++i)
            #pragma unroll
            for (int j = 0; j < 4; ++j)
                acc[i][j] = __builtin_amdgcn_mfma_f32_16x16x32_f16(af[i], bf[j], acc[i][j], 0, 0, 0);
    }

    const int quad = lane >> 4, cc = lane & 15;
    __syncthreads();

    #pragma unroll
    for (int i = 0; i < 2; ++i) {
        #pragma unroll
        for (int j = 0; j < 4; ++j) {
            const int col = wn * 64 + j * 16 + cc;
            #pragma unroll
            for (int r = 0; r < 4; ++r) {
                const int rl = wm * 32 + i * 16 + quad * 4 + r;
                Pt[col * 136 + rl] = (f16)(__expf(acc[i][j][r] - sqs[rl]) * MSCALE);
            }
        }
    }
    {
        // V transpose staging: 512 threads, each handles 16 elems of one n-row
        const int vn = t >> 2;
        const int vhf = (t & 3) * 16;
        const f16* vbase = vh + (((size_t)bh << 10) + nt * 128 + vn) * 64 + vhf;
        #pragma unroll
        for (int k = 0; k < 2; ++k) {
            f16x8 vv = *(const f16x8*)&vbase[k * 8];
            #pragma unroll
            for (int e = 0; e < 8; ++e)
                vT[(vhf + k * 8 + e) * 136 + vn] = vv[e];
        }
    }
    __syncthreads();

    f32x4 acc2[2][2] = {};
    #pragma unroll
    for (int kt = 0; kt < 4; ++kt) {
        const int kb = kt * 32 + (lane >> 4) * 8;
        f16x8 af2[2], bf2[2];
        #pragma unroll
        for (int i = 0; i < 2; ++i)
            af2[i] = *(const f16x8*)&Pt[(wm * 32 + i * 16 + (lane & 15)) * 136 + kb];
        #pragma unroll
        for (int j = 0; j < 2; ++j)
            bf2[j] = *(const f16x8*)&vT[(wn * 32 + j * 16 + (lane & 15)) * 136 + kb];
        #pragma unroll
        for (int i = 0; i < 2; ++i)
            #pragma unroll
            for (int j = 0; j < 2; ++j)
                acc2[i][j] = __builtin_amdgcn_mfma_f32_16x16x32_f16(af2[i], bf2[j], acc2[i][j], 0, 0, 0);
    }

    // plain stores to this nt's partial buffer
    float* kvo = ((nt < 4) ? (kvpA + (size_t)nt * 786432)
                           : (kvpB + (size_t)(nt - 4) * 786432)) + (size_t)bh * 8192;
    #pragma unroll
    for (int i = 0; i < 2; ++i) {
        #pragma unroll
        for (int j = 0; j < 2; ++j) {
            const int d = wn * 32 + j * 16 + cc;
            #pragma unroll
            for (int r = 0; r < 4; ++r) {
                const int m = wm * 32 + i * 16 + quad * 4 + r;
                kvo[m * 64 + d] = acc2[i][j][r];
            }
        }
    }
    {
        // colsum over n: 512 threads, each sums 32 of the 128 n's for one m
        const int sm = t >> 2, shf = (t & 3) * 32;
        float sp = 0.f;
        #pragma unroll
        for (int k = 0; k < 4; ++k) {
            f16x8 pv = *(const f16x8*)&Pt[sm * 136 + shf + k * 8];
            #pragma unroll
            for (int e = 0; e < 8; ++e) sp += (float)pv[e];
        }
        sp += __shfl_xor(sp, 1, 64);
        sp += __shfl_xor(sp, 2, 64);
        if ((t & 3) == 0) sfp[((size_t)nt * 96 + bh) * 128 + sm] = sp;
    }
}

// ---------------- reduce the 8 per-nt partials -> kvf, sf (BW-bound, ~28 MB) ----------------
__global__ __launch_bounds__(256) void kv_reduce(
        const float* __restrict__ kvpA, const float* __restrict__ kvpB,
        const float* __restrict__ sfp, float* __restrict__ kvf, float* __restrict__ sf)
{
    const int bh = blockIdx.x;
    if (blockIdx.y == 8) {
        const int t = threadIdx.x;
        if (t < 128) {
            float s = 0.f;
            #pragma unroll
            for (int nt = 0; nt < 8; ++nt)
                s += sfp[((size_t)nt * 96 + bh) * 128 + t];
            sf[(size_t)bh * 128 + t] = s;
        }
        return;
    }
    const size_t base = (size_t)bh * 8192 + blockIdx.y * 1024 + threadIdx.x * 4;
    float4 s = *(const float4*)&kvpA[base];
    #pragma unroll
    for (int nt = 1; nt < 4; ++nt) {
        float4 v = *(const float4*)&kvpA[(size_t)nt * 786432 + base];
        s.x += v.x; s.y += v.y; s.z += v.z; s.w += v.w;
    }
    #pragma unroll
    for (int nt = 0; nt < 4; ++nt) {
        float4 v = *(const float4*)&kvpB[(size_t)nt * 786432 + base];
        s.x += v.x; s.y += v.y; s.z += v.z; s.w += v.w;
    }
    *(float4*)&kvf[base] = s;
}

// ---------------- fused feat(q): 8-wave (512t) occupancy variant ----------------
__global__ __launch_bounds__(512) void feat_apply(
        const f16* __restrict__ zq, const f16* __restrict__ Rt,
        const float* __restrict__ sqq, const float* __restrict__ kvf,
        const float* __restrict__ sf, f16* __restrict__ ohA)
{
    __shared__ __align__(16) char smem[52224];
    f16* As = (f16*)smem;
    f16* Bs = (f16*)(smem + 16384);
    f16* Pn = (f16*)smem;              // [128 n][136 m]
    f16* kvT = (f16*)(smem + 34816);   // [64 d][136 m]
    __shared__ float sqs[128], ssm[128], dns[128];

    const int t = threadIdx.x;
    const int wave = t >> 6, lane = t & 63;
    const int wm = wave >> 1, wn = wave & 1;   // 4M(32-row) x 2N
    const int nt = blockIdx.x, bh = blockIdx.y;
    const int b = bh / PH, h = bh % PH;

    const f16* A = zq + (((size_t)bh << 10) + nt * 128) * 64;
    const f16* Bm = Rt + (size_t)h * (PM * PD);

    if (t < 128) {
        sqs[t] = sqq[((size_t)bh << 10) + nt * 128 + t];
        ssm[t] = sf[(size_t)bh * 128 + t];
    }

    const int rowi = lane >> 3;
    const int cb = (lane & 7) ^ ((lane >> 4) & 3);
    const f16* ApE = A + (size_t)(wave * 16 + rowi) * 64 + cb * 8;
    const f16* ApO = A + (size_t)(wave * 16 + rowi) * 64 + (cb ^ 4) * 8;
    const f16* BpE = Bm + (size_t)(wave * 16 + rowi) * 64 + cb * 8;
    const f16* BpO = Bm + (size_t)(wave * 16 + rowi) * 64 + (cb ^ 4) * 8;
    f16* AsB = &As[wave * 16 * 64];
    f16* BsB = &Bs[wave * 16 * 64];
    GLL(ApE,           AsB);
    GLL(ApO + 8 * 64,  AsB + 8 * 64);
    GLL(BpE,           BsB);
    GLL(BpO + 8 * 64,  BsB + 8 * 64);
    __syncthreads();

    const int q4 = lane >> 4;
    f32x4 acc[2][4] = {};
    #pragma unroll
    for (int kh = 0; kh < 2; ++kh) {
        f16x8 af[2], bf[4];
        #pragma unroll
        for (int i = 0; i < 2; ++i) {
            const int r = wm * 32 + i * 16 + (lane & 15);
            const int p = (kh * 4 + q4) ^ ((r >> 1) & 7);
            af[i] = *(const f16x8*)&As[r * 64 + p * 8];
        }
        #pragma unroll
        for (int j = 0; j < 4; ++j) {
            const int r = wn * 64 + j * 16 + (lane & 15);
            const int p = (kh * 4 + q4) ^ ((r >> 1) & 7);
            bf[j] = *(const f16x8*)&Bs[r * 64 + p * 8];
        }
        #pragma unroll
        for (int i = 0; i < 2; ++i)
            #pragma unroll
            for (int j = 0; j < 4; ++j)
                acc[i][j] = __builtin_amdgcn_mfma_f32_16x16x32_f16(af[i], bf[j], acc[i][j], 0, 0, 0);
    }

    const int quad = lane >> 4, cc = lane & 15;
    __syncthreads();

    #pragma unroll
    for (int i = 0; i < 2; ++i) {
        #pragma unroll
        for (int j = 0; j < 4; ++j) {
            const int col = wn * 64 + j * 16 + cc;
            #pragma unroll
            for (int r = 0; r < 4; ++r) {
                const int rl = wm * 32 + i * 16 + quad * 4 + r;
                Pn[rl * 136 + col] = (f16)(__expf(acc[i][j][r] - sqs[rl]) * MSCALE);
            }
        }
    }
    {
        // KV transpose staging: 512 threads, each 16 f32 of one m-row
        const int m = t >> 2;
        const int dh2 = (t & 3) * 16;
        const float* kvb = kvf + ((size_t)bh * 128 + m) * 64 + dh2;
        #pragma unroll
        for (int k = 0; k < 4; ++k) {
            float4 k4 = *(const float4*)&kvb[k * 4];
            kvT[(dh2 + k * 4 + 0) * 136 + m] = (f16)k4.x;
            kvT[(dh2 + k * 4 + 1) * 136 + m] = (f16)k4.y;
            kvT[(dh2 + k * 4 + 2) * 136 + m] = (f16)k4.z;
            kvT[(dh2 + k * 4 + 3) * 136 + m] = (f16)k4.w;
        }
    }
    __syncthreads();

    {
        // denom: 512 threads, each sums 32 of 128 m-terms for one n
        const int n = t >> 2, mh = (t & 3) * 32;
        float p = 0.f;
        #pragma unroll
        for (int k = 0; k < 4; ++k) {
            f16x8 pv = *(const f16x8*)&Pn[n * 136 + mh + k * 8];
            #pragma unroll
            for (int e = 0; e < 8; ++e)
                p += (float)pv[e] * ssm[mh + k * 8 + e];
        }
        p += __shfl_xor(p, 1, 64);
        p += __shfl_xor(p, 2, 64);
        if ((t & 3) == 0) dns[n] = (p < 1e-12f) ? 1e-12f : p;
    }
    __syncthreads();

    f32x4 acc3[2][2] = {};
    #pragma unroll
    for (int kt = 0; kt < 4; ++kt) {
        const int kb = kt * 32 + (lane >> 4) * 8;
        f16x8 af3[2], bf3[2];
        #pragma unroll
        for (int i = 0; i < 2; ++i)
            af3[i] = *(const f16x8*)&Pn[(wm * 32 + i * 16 + (lane & 15)) * 136 + kb];
        #pragma unroll
        for (int j = 0; j < 2; ++j)
            bf3[j] = *(const f16x8*)&kvT[(wn * 32 + j * 16 + (lane & 15)) * 136 + kb];
        #pragma unroll
        for (int i = 0; i < 2; ++i)
            #pragma unroll
            for (int j = 0; j < 2; ++j)
                acc3[i][j] = __builtin_amdgcn_mfma_f32_16x16x32_f16(af3[i], bf3[j], acc3[i][j], 0, 0, 0);
    }

    f16* ob = ohA + ((size_t)(b * PN) + nt * 128) * PC + h * PD;
    #pragma unroll
    for (int i = 0; i < 2; ++i) {
        #pragma unroll
        for (int j = 0; j < 2; ++j) {
            const int d = wn * 32 + j * 16 + cc;
            #pragma unroll
            for (int r = 0; r < 4; ++r) {
                const int n = wm * 32 + i * 16 + quad * 4 + r;
                ob[(size_t)n * PC + d] = (f16)(acc3[i][j][r] / dns[n]);
            }
        }
    }
}

// ---------------- output projection GEMM (BK=64, BN=64): round-0 proven 4-wave ----------------
// r5 measured: 8-wave 32x32-per-wave variant regressed ~10us. Keep 4-wave.
__global__ __launch_bounds__(256) void gemm_proj(
        const f16* __restrict__ A,    // [8192][768]
        const f16* __restrict__ Bm,   // [768][768]
        float* __restrict__ Cm, const float* __restrict__ bias)
{
    __shared__ f16 As[128 * 64];
    __shared__ f16 Bs[64 * 64];
    const int t = threadIdx.x;
    const int wave = t >> 6, lane = t & 63;
    const int wm = wave >> 1, wn = wave & 1;
    const int bi = blockIdx.x * 128, bj = blockIdx.y * 64;

    f32x4 acc[4][2] = {};

    const int rowi = lane >> 3;
    const int cb = (lane & 7) ^ ((lane >> 4) & 3);
    const f16* ApE = A + (size_t)(bi + wave * 32 + rowi) * PC + cb * 8;
    const f16* ApO = A + (size_t)(bi + wave * 32 + rowi) * PC + (cb ^ 4) * 8;
    const f16* BpE = Bm + (size_t)(bj + wave * 16 + rowi) * PC + cb * 8;
    const f16* BpO = Bm + (size_t)(bj + wave * 16 + rowi) * PC + (cb ^ 4) * 8;
    f16* AsB = &As[wave * 32 * 64];
    f16* BsB = &Bs[wave * 16 * 64];

    const int q4 = lane >> 4;
    for (int kt = 0; kt < 12; ++kt) {
        const int k0 = kt * 64;
        __syncthreads();
        GLL(ApE + k0,               AsB);
        GLL(ApO + k0 + (size_t) 8 * PC, AsB + 8 * 64);
        GLL(ApE + k0 + (size_t)16 * PC, AsB + 16 * 64);
        GLL(ApO + k0 + (size_t)24 * PC, AsB + 24 * 64);
        GLL(BpE + k0,               BsB);
        GLL(BpO + k0 + (size_t) 8 * PC, BsB + 8 * 64);
        __syncthreads();

        #pragma unroll
        for (int kh = 0; kh < 2; ++kh) {
            f16x8 af[4], bf[2];
            #pragma unroll
            for (int i = 0; i < 4; ++i) {
                const int r = wm * 64 + i * 16 + (lane & 15);
                const int p = (kh * 4 + q4) ^ ((r >> 1) & 7);
                af[i] = *(const f16x8*)&As[r * 64 + p * 8];
            }
            #pragma unroll
            for (int j = 0; j < 2; ++j) {
                const int r = wn * 32 + j * 16 + (lane & 15);
                const int p = (kh * 4 + q4) ^ ((r >> 1) & 7);
                bf[j] = *(const f16x8*)&Bs[r * 64 + p * 8];
            }
            #pragma unroll
            for (int i = 0; i < 4; ++i)
                #pragma unroll
                for (int j = 0; j < 2; ++j)
                    acc[i][j] = __builtin_amdgcn_mfma_f32_16x16x32_f16(af[i], bf[j], acc[i][j], 0, 0, 0);
        }
    }

    const int cr = (lane >> 4) * 4, cc = lane & 15;
    #pragma unroll
    for (int i = 0; i < 4; ++i) {
        const int row = bi + wm * 64 + i * 16 + cr;
        #pragma unroll
        for (int j = 0; j < 2; ++j) {
            const int col = bj + wn * 32 + j * 16 + cc;
            const float bv = bias[col];
            #pragma unroll
            for (int r = 0; r < 4; ++r)
                Cm[(size_t)(row + r) * PC + col] = acc[i][j][r] + bv;
        }
    }
}

extern "C" void kernel_launch(void* const* d_in, const int* in_sizes, int n_in,
                              void* d_out, int out_size, void* d_ws, size_t ws_size,
                              hipStream_t stream) {
    const float* x      = (const float*)d_in[0];
    const float* qkv_w  = (const float*)d_in[1];
    const float* proj_w = (const float*)d_in[2];
    const float* proj_b = (const float*)d_in[3];
    const float* rm     = (const float*)d_in[4];
    float* out = (float*)d_out;

    char* ws = (char*)d_ws;
    f16*   Ax   = (f16*)(ws);                     // [8192][768]      = 12,582,912
    f16*   Bqk  = (f16*)(ws + 12582912);          // [2304][768]      =  3,538,944
    f16*   Bp   = (f16*)(ws + 16121856);          // [768][768]       =  1,179,648
    f16*   Rt   = (f16*)(ws + 17301504);          // [12][128][64]    =    196,608
    f16*   zq   = (f16*)(ws + 17498112);          // [96][1024][64]   = 12,582,912
    f16*   zk   = (f16*)(ws + 30081024);          // [96][1024][64]   = 12,582,912
    f16*   vh   = (f16*)(ws + 42663936);          // [96][1024][64]   = 12,582,912
    float* sqq  = (float*)(ws + 55246848);        // [96][1024] f32   =    393,216
    float* sqk  = (float*)(ws + 55640064);        // [96][1024] f32   =    393,216
    float* kvf  = (float*)(ws + 56033280);        // [96][128][64] f32=  3,145,728
    float* sf   = (float*)(ws + 59179008);        // [96][128] f32    =     49,152
    f16*   ohA  = (f16*)(ws + 59228160);          // [8192][768]      = 12,582,912

    // partial-kv buffers ALIAS dead regions (no extra workspace):
    //   kvpA (nt 0-3) -> Ax region (dead after gemm_qkv)
    //   kvpB (nt 4-7) -> ohA region (not live until feat_apply, after kv_reduce)
    //   sfp           -> Bqk region (dead after gemm_qkv)
    float* kvpA = (float*)(ws);                   // 4 * 96*128*64 f32 = 12,582,912
    float* kvpB = (float*)(ws + 59228160);        // 4 * 96*128*64 f32 = 12,582,912
    float* sfp  = (float*)(ws + 12582912);        // [8][96][128] f32  =    393,216

    // 1) conversions
    conv_all<<<11276, 192, 0, stream>>>(x, qkv_w, proj_w, rm, Ax, Bqk, Bp, Rt);

    // 2) fused qkv projection (64x128 tile, 256t, max co-residency)
    gemm_qkv<<<dim3(128, 18), 256, 0, stream>>>(Ax, Bqk, zq, zk, vh, sqq, sqk);

    // 3) fused feat(k) + kf^T@V + colsum -> per-nt partials (8-wave)
    feat_kv<<<dim3(8, 96), 512, 0, stream>>>(zk, Rt, sqk, vh, kvpA, kvpB, sfp);

    // 4) reduce partials -> kvf, sf
    kv_reduce<<<dim3(96, 9), 256, 0, stream>>>(kvpA, kvpB, sfp, kvf, sf);

    // 5) fused feat(q) + denom + P@KV -> ohA (8-wave)
    feat_apply<<<dim3(8, 96), 512, 0, stream>>>(zq, Rt, sqq, kvf, sf, ohA);

    // 6) out = oh @ proj_w^T + proj_b
    gemm_proj<<<dim3(64, 12), 256, 0, stream>>>(ohA, Bp, out, proj_b);
}

// Round 8
// 171.717 us; speedup vs baseline: 1.0475x; 1.0045x over previous
//
#include <hip/hip_runtime.h>
#include <hip/hip_bf16.h>

// Problem constants: B=8, N=1024, C=768, H=12, D=64, M=128
#define PB 8
#define PN 1024
#define PC 768
#define PH 12
#define PD 64
#define PM 128
#define SQ 0.35355339059327373f      // (D^-0.5)^0.5 = D^-0.25
#define MSCALE 0.08838834764831843f  // M^-0.5

typedef _Float16 f16;
typedef f16 f16x8 __attribute__((ext_vector_type(8)));
typedef f16 f16x4 __attribute__((ext_vector_type(4)));
typedef float f32x4 __attribute__((ext_vector_type(4)));

#define GLL(src, dst) __builtin_amdgcn_global_load_lds( \
    (const __attribute__((address_space(1))) void*)(src), \
    (__attribute__((address_space(3))) void*)(dst), 16, 0, 0)

// ---------------- conversions, one launch ----------------
// [0,8192): x; [8192,10496): qkv_w; [10496,11264): proj_w; [11264,11276): Rt
__global__ __launch_bounds__(192) void conv_all(
        const float* __restrict__ x, const float* __restrict__ qkv_w,
        const float* __restrict__ proj_w, const float* __restrict__ rm,
        f16* __restrict__ Ax, f16* __restrict__ Bqk, f16* __restrict__ Bp,
        f16* __restrict__ Rt)
{
    const int bid = blockIdx.x;
    const int t = threadIdx.x;
    if (bid < 11264) {
        const float* src; f16* dst; int r;
        if (bid < 8192)       { src = x;      dst = Ax;  r = bid; }
        else if (bid < 10496) { src = qkv_w;  dst = Bqk; r = bid - 8192; }
        else                  { src = proj_w; dst = Bp;  r = bid - 10496; }
        const int c = t * 4;
        float4 v = *(const float4*)&src[(size_t)r * PC + c];
        f16x4 hv;
        hv.x = (f16)v.x; hv.y = (f16)v.y; hv.z = (f16)v.z; hv.w = (f16)v.w;
        *(f16x4*)&dst[(size_t)r * PC + c] = hv;
    } else {
        const int h = bid - 11264;
        for (int e = t; e < PD * PM; e += 192)
            Rt[(size_t)h * 8192 + e] = (f16)rm[(size_t)h * 8192 + (e & 63) * PM + (e >> 6)];
    }
}

// ---------------- fused qkv GEMM: 64x128 tile, 256t/4 waves (r6 proven, 42us) ----------------
// Occupancy ladder measured in-session: 128^2/4w 84VGPR = 56us ->
// 128^2/8w 48VGPR = 46us -> 64x128/4w 48VGPR 24KB LDS = 42us. Keep.
__global__ __launch_bounds__(256) void gemm_qkv(
        const f16* __restrict__ A,    // [8192][768]
        const f16* __restrict__ Bm,   // [2304][768]
        f16* __restrict__ zq, f16* __restrict__ zk, f16* __restrict__ vh,
        float* __restrict__ sqq, float* __restrict__ sqk)
{
    __shared__ f16 As[64 * 64];
    __shared__ f16 Bs[128 * 64];
    const int t = threadIdx.x;
    const int wave = t >> 6, lane = t & 63;
    const int wm = wave >> 1, wn = wave & 1;     // 2M x 2N, wave owns 32x64
    const int bi = blockIdx.x * 64, bj = blockIdx.y * 128;

    f32x4 acc[2][4] = {};

    const int rowi = lane >> 3;
    const int cb = (lane & 7) ^ ((lane >> 4) & 3);
    const f16* ApE = A + (size_t)(bi + wave * 16 + rowi) * PC + cb * 8;
    const f16* ApO = A + (size_t)(bi + wave * 16 + rowi) * PC + (cb ^ 4) * 8;
    const f16* BpE = Bm + (size_t)(bj + wave * 32 + rowi) * PC + cb * 8;
    const f16* BpO = Bm + (size_t)(bj + wave * 32 + rowi) * PC + (cb ^ 4) * 8;
    f16* AsB = &As[wave * 16 * 64];
    f16* BsB = &Bs[wave * 32 * 64];

    const int q4 = lane >> 4;
    for (int kt = 0; kt < 12; ++kt) {
        const int k0 = kt * 64;
        __syncthreads();
        GLL(ApE + k0,                   AsB);
        GLL(ApO + k0 + (size_t) 8 * PC, AsB + 8 * 64);
        GLL(BpE + k0,                   BsB);
        GLL(BpO + k0 + (size_t) 8 * PC, BsB + 8 * 64);
        GLL(BpE + k0 + (size_t)16 * PC, BsB + 16 * 64);
        GLL(BpO + k0 + (size_t)24 * PC, BsB + 24 * 64);
        __syncthreads();

        #pragma unroll
        for (int kh = 0; kh < 2; ++kh) {
            f16x8 af[2], bf[4];
            #pragma unroll
            for (int i = 0; i < 2; ++i) {
                const int r = wm * 32 + i * 16 + (lane & 15);
                const int p = (kh * 4 + q4) ^ ((r >> 1) & 7);
                af[i] = *(const f16x8*)&As[r * 64 + p * 8];
            }
            #pragma unroll
            for (int j = 0; j < 4; ++j) {
                const int r = wn * 64 + j * 16 + (lane & 15);
                const int p = (kh * 4 + q4) ^ ((r >> 1) & 7);
                bf[j] = *(const f16x8*)&Bs[r * 64 + p * 8];
            }
            #pragma unroll
            for (int i = 0; i < 2; ++i)
                #pragma unroll
                for (int j = 0; j < 4; ++j)
                    acc[i][j] = __builtin_amdgcn_mfma_f32_16x16x32_f16(af[i], bf[j], acc[i][j], 0, 0, 0);
        }
    }

    const int quad = lane >> 4, cc = lane & 15;
    const int colbase = bj + wn * 64;
    const int b = bi >> 10;
    if (colbase < 1536) {
        const int which = colbase >= 768;
        const int h = (colbase - which * 768) >> 6;
        f16* zdst = which ? zk : zq;
        float* sdst = which ? sqk : sqq;
        const size_t bh = (size_t)(b * PH + h);
        #pragma unroll
        for (int i = 0; i < 2; ++i) {
            const int row0 = bi + wm * 32 + i * 16 + quad * 4;
            #pragma unroll
            for (int r = 0; r < 4; ++r) {
                const int n = (row0 + r) & 1023;
                f16 zh[4]; float psq = 0.f;
                #pragma unroll
                for (int j = 0; j < 4; ++j) {
                    zh[j] = (f16)(acc[i][j][r] * SQ);
                    float zf = (float)zh[j];
                    psq += zf * zf;
                }
                psq += __shfl_xor(psq, 1, 64);
                psq += __shfl_xor(psq, 2, 64);
                psq += __shfl_xor(psq, 4, 64);
                psq += __shfl_xor(psq, 8, 64);
                if (cc == 0) sdst[(bh << 10) + n] = 0.5f * psq;
                f16* zp = zdst + (((bh << 10) + n) << 6);
                #pragma unroll
                for (int j = 0; j < 4; ++j) zp[j * 16 + cc] = zh[j];
            }
        }
    } else {
        const int h = (colbase - 1536) >> 6;
        const size_t bh = (size_t)(b * PH + h);
        #pragma unroll
        for (int i = 0; i < 2; ++i) {
            const int row0 = bi + wm * 32 + i * 16 + quad * 4;
            #pragma unroll
            for (int r = 0; r < 4; ++r) {
                const int n = (row0 + r) & 1023;
                f16* vp = vh + (((bh << 10) + n) << 6);
                #pragma unroll
                for (int j = 0; j < 4; ++j) vp[j * 16 + cc] = (f16)acc[i][j][r];
            }
        }
    }
}

// ---------------- fused feat(k): 8-wave, packed P-writes ----------------
// P-write: the 4 r-values per (i,j) are 4 consecutive n in Pt[m][n] ->
// one ds_write_b64 (f16x4) instead of 4 scalar writes (32 -> 8 LDS instr).
__global__ __launch_bounds__(512) void feat_kv(
        const f16* __restrict__ zk, const f16* __restrict__ Rt,
        const float* __restrict__ sqk, const f16* __restrict__ vh,
        float* __restrict__ kvpA, float* __restrict__ kvpB, float* __restrict__ sfp)
{
    __shared__ __align__(16) char smem[52224];
    f16* As = (f16*)smem;              // stage z [128][64] (16KB)
    f16* Bs = (f16*)(smem + 16384);    // stage Rt [128][64] (16KB)
    f16* Pt = (f16*)smem;              // [128 m][136 n] aliases stages
    f16* vT = (f16*)(smem + 34816);    // [64 d][136 n]
    __shared__ float sqs[128];

    const int t = threadIdx.x;
    const int wave = t >> 6, lane = t & 63;
    const int wm = wave >> 1, wn = wave & 1;   // 4M(32-row) x 2N(64-col)
    const int nt = blockIdx.x, bh = blockIdx.y;
    const int h = bh % PH;

    const f16* A = zk + (((size_t)bh << 10) + nt * 128) * 64;
    const f16* Bm = Rt + (size_t)h * (PM * PD);

    if (t < 128) sqs[t] = sqk[((size_t)bh << 10) + nt * 128 + t];

    const int rowi = lane >> 3;
    const int cb = (lane & 7) ^ ((lane >> 4) & 3);
    const f16* ApE = A + (size_t)(wave * 16 + rowi) * 64 + cb * 8;
    const f16* ApO = A + (size_t)(wave * 16 + rowi) * 64 + (cb ^ 4) * 8;
    const f16* BpE = Bm + (size_t)(wave * 16 + rowi) * 64 + cb * 8;
    const f16* BpO = Bm + (size_t)(wave * 16 + rowi) * 64 + (cb ^ 4) * 8;
    f16* AsB = &As[wave * 16 * 64];
    f16* BsB = &Bs[wave * 16 * 64];
    GLL(ApE,           AsB);
    GLL(ApO + 8 * 64,  AsB + 8 * 64);
    GLL(BpE,           BsB);
    GLL(BpO + 8 * 64,  BsB + 8 * 64);
    __syncthreads();

    const int q4 = lane >> 4;
    f32x4 acc[2][4] = {};
    #pragma unroll
    for (int kh = 0; kh < 2; ++kh) {
        f16x8 af[2], bf[4];
        #pragma unroll
        for (int i = 0; i < 2; ++i) {
            const int r = wm * 32 + i * 16 + (lane & 15);
            const int p = (kh * 4 + q4) ^ ((r >> 1) & 7);
            af[i] = *(const f16x8*)&As[r * 64 + p * 8];
        }
        #pragma unroll
        for (int j = 0; j < 4; ++j) {
            const int r = wn * 64 + j * 16 + (lane & 15);
            const int p = (kh * 4 + q4) ^ ((r >> 1) & 7);
            bf[j] = *(const f16x8*)&Bs[r * 64 + p * 8];
        }
        #pragma unroll
        for (int i = 0; i < 2; ++i)
            #pragma unroll
            for (int j = 0; j < 4; ++j)
                acc[i][j] = __builtin_amdgcn_mfma_f32_16x16x32_f16(af[i], bf[j], acc[i][j], 0, 0, 0);
    }

    const int quad = lane >> 4, cc = lane & 15;
    __syncthreads();

    #pragma unroll
    for (int i = 0; i < 2; ++i) {
        const int rl0 = wm * 32 + i * 16 + quad * 4;
        #pragma unroll
        for (int j = 0; j < 4; ++j) {
            const int col = wn * 64 + j * 16 + cc;
            f16x4 pk;
            #pragma unroll
            for (int r = 0; r < 4; ++r)
                pk[r] = (f16)(__expf(acc[i][j][r] - sqs[rl0 + r]) * MSCALE);
            *(f16x4*)&Pt[col * 136 + rl0] = pk;
        }
    }
    {
        // V transpose staging: 512 threads, each handles 16 elems of one n-row
        const int vn = t >> 2;
        const int vhf = (t & 3) * 16;
        const f16* vbase = vh + (((size_t)bh << 10) + nt * 128 + vn) * 64 + vhf;
        #pragma unroll
        for (int k = 0; k < 2; ++k) {
            f16x8 vv = *(const f16x8*)&vbase[k * 8];
            #pragma unroll
            for (int e = 0; e < 8; ++e)
                vT[(vhf + k * 8 + e) * 136 + vn] = vv[e];
        }
    }
    __syncthreads();

    f32x4 acc2[2][2] = {};
    #pragma unroll
    for (int kt = 0; kt < 4; ++kt) {
        const int kb = kt * 32 + (lane >> 4) * 8;
        f16x8 af2[2], bf2[2];
        #pragma unroll
        for (int i = 0; i < 2; ++i)
            af2[i] = *(const f16x8*)&Pt[(wm * 32 + i * 16 + (lane & 15)) * 136 + kb];
        #pragma unroll
        for (int j = 0; j < 2; ++j)
            bf2[j] = *(const f16x8*)&vT[(wn * 32 + j * 16 + (lane & 15)) * 136 + kb];
        #pragma unroll
        for (int i = 0; i < 2; ++i)
            #pragma unroll
            for (int j = 0; j < 2; ++j)
                acc2[i][j] = __builtin_amdgcn_mfma_f32_16x16x32_f16(af2[i], bf2[j], acc2[i][j], 0, 0, 0);
    }

    // plain stores to this nt's partial buffer
    float* kvo = ((nt < 4) ? (kvpA + (size_t)nt * 786432)
                           : (kvpB + (size_t)(nt - 4) * 786432)) + (size_t)bh * 8192;
    #pragma unroll
    for (int i = 0; i < 2; ++i) {
        #pragma unroll
        for (int j = 0; j < 2; ++j) {
            const int d = wn * 32 + j * 16 + cc;
            #pragma unroll
            for (int r = 0; r < 4; ++r) {
                const int m = wm * 32 + i * 16 + quad * 4 + r;
                kvo[m * 64 + d] = acc2[i][j][r];
            }
        }
    }
    {
        // colsum over n: 512 threads, each sums 32 of the 128 n's for one m
        const int sm = t >> 2, shf = (t & 3) * 32;
        float sp = 0.f;
        #pragma unroll
        for (int k = 0; k < 4; ++k) {
            f16x8 pv = *(const f16x8*)&Pt[sm * 136 + shf + k * 8];
            #pragma unroll
            for (int e = 0; e < 8; ++e) sp += (float)pv[e];
        }
        sp += __shfl_xor(sp, 1, 64);
        sp += __shfl_xor(sp, 2, 64);
        if ((t & 3) == 0) sfp[((size_t)nt * 96 + bh) * 128 + sm] = sp;
    }
}

// ---------------- reduce the 8 per-nt partials -> kvf, sf (BW-bound, ~28 MB) ----------------
__global__ __launch_bounds__(256) void kv_reduce(
        const float* __restrict__ kvpA, const float* __restrict__ kvpB,
        const float* __restrict__ sfp, float* __restrict__ kvf, float* __restrict__ sf)
{
    const int bh = blockIdx.x;
    if (blockIdx.y == 8) {
        const int t = threadIdx.x;
        if (t < 128) {
            float s = 0.f;
            #pragma unroll
            for (int nt = 0; nt < 8; ++nt)
                s += sfp[((size_t)nt * 96 + bh) * 128 + t];
            sf[(size_t)bh * 128 + t] = s;
        }
        return;
    }
    const size_t base = (size_t)bh * 8192 + blockIdx.y * 1024 + threadIdx.x * 4;
    float4 s = *(const float4*)&kvpA[base];
    #pragma unroll
    for (int nt = 1; nt < 4; ++nt) {
        float4 v = *(const float4*)&kvpA[(size_t)nt * 786432 + base];
        s.x += v.x; s.y += v.y; s.z += v.z; s.w += v.w;
    }
    #pragma unroll
    for (int nt = 0; nt < 4; ++nt) {
        float4 v = *(const float4*)&kvpB[(size_t)nt * 786432 + base];
        s.x += v.x; s.y += v.y; s.z += v.z; s.w += v.w;
    }
    *(float4*)&kvf[base] = s;
}

// ---------------- fused feat(q): 8-wave, swapped MFMA1 -> packed P-writes ----------------
// MFMA1 operands swapped (af<-Rt rows m, bf<-zq rows n): acc rows=m, cols=n,
// so the 4 r-values are 4 consecutive m in Pn[n][m] -> f16x4 ds_write.
// sqs is indexed by col (n) now. Downstream (denom, MFMA3, epilogue) unchanged.
__global__ __launch_bounds__(512) void feat_apply(
        const f16* __restrict__ zq, const f16* __restrict__ Rt,
        const float* __restrict__ sqq, const float* __restrict__ kvf,
        const float* __restrict__ sf, f16* __restrict__ ohA)
{
    __shared__ __align__(16) char smem[52224];
    f16* As = (f16*)smem;
    f16* Bs = (f16*)(smem + 16384);
    f16* Pn = (f16*)smem;              // [128 n][136 m]
    f16* kvT = (f16*)(smem + 34816);   // [64 d][136 m]
    __shared__ float sqs[128], ssm[128], dns[128];

    const int t = threadIdx.x;
    const int wave = t >> 6, lane = t & 63;
    const int wm = wave >> 1, wn = wave & 1;   // 4M x 2N
    const int nt = blockIdx.x, bh = blockIdx.y;
    const int b = bh / PH, h = bh % PH;

    const f16* A = zq + (((size_t)bh << 10) + nt * 128) * 64;
    const f16* Bm = Rt + (size_t)h * (PM * PD);

    if (t < 128) {
        sqs[t] = sqq[((size_t)bh << 10) + nt * 128 + t];
        ssm[t] = sf[(size_t)bh * 128 + t];
    }

    const int rowi = lane >> 3;
    const int cb = (lane & 7) ^ ((lane >> 4) & 3);
    const f16* ApE = A + (size_t)(wave * 16 + rowi) * 64 + cb * 8;
    const f16* ApO = A + (size_t)(wave * 16 + rowi) * 64 + (cb ^ 4) * 8;
    const f16* BpE = Bm + (size_t)(wave * 16 + rowi) * 64 + cb * 8;
    const f16* BpO = Bm + (size_t)(wave * 16 + rowi) * 64 + (cb ^ 4) * 8;
    f16* AsB = &As[wave * 16 * 64];
    f16* BsB = &Bs[wave * 16 * 64];
    GLL(ApE,           AsB);
    GLL(ApO + 8 * 64,  AsB + 8 * 64);
    GLL(BpE,           BsB);
    GLL(BpO + 8 * 64,  BsB + 8 * 64);
    __syncthreads();

    const int q4 = lane >> 4;
    f32x4 acc[2][4] = {};
    #pragma unroll
    for (int kh = 0; kh < 2; ++kh) {
        f16x8 af[2], bf[4];
        // SWAPPED: A-operand = Rt rows (m, from Bs), B-operand = zq rows (n, from As)
        #pragma unroll
        for (int i = 0; i < 2; ++i) {
            const int r = wm * 32 + i * 16 + (lane & 15);
            const int p = (kh * 4 + q4) ^ ((r >> 1) & 7);
            af[i] = *(const f16x8*)&Bs[r * 64 + p * 8];
        }
        #pragma unroll
        for (int j = 0; j < 4; ++j) {
            const int r = wn * 64 + j * 16 + (lane & 15);
            const int p = (kh * 4 + q4) ^ ((r >> 1) & 7);
            bf[j] = *(const f16x8*)&As[r * 64 + p * 8];
        }
        #pragma unroll
        for (int i = 0; i < 2; ++i)
            #pragma unroll
            for (int j = 0; j < 4; ++j)
                acc[i][j] = __builtin_amdgcn_mfma_f32_16x16x32_f16(af[i], bf[j], acc[i][j], 0, 0, 0);
    }

    const int quad = lane >> 4, cc = lane & 15;
    __syncthreads();

    #pragma unroll
    for (int i = 0; i < 2; ++i) {
        const int m0 = wm * 32 + i * 16 + quad * 4;   // rows = m
        #pragma unroll
        for (int j = 0; j < 4; ++j) {
            const int col = wn * 64 + j * 16 + cc;    // cols = n
            const float sq = sqs[col];
            f16x4 pk;
            #pragma unroll
            for (int r = 0; r < 4; ++r)
                pk[r] = (f16)(__expf(acc[i][j][r] - sq) * MSCALE);
            *(f16x4*)&Pn[col * 136 + m0] = pk;
        }
    }
    {
        // KV transpose staging: 512 threads, each 16 f32 of one m-row
        const int m = t >> 2;
        const int dh2 = (t & 3) * 16;
        const float* kvb = kvf + ((size_t)bh * 128 + m) * 64 + dh2;
        #pragma unroll
        for (int k = 0; k < 4; ++k) {
            float4 k4 = *(const float4*)&kvb[k * 4];
            kvT[(dh2 + k * 4 + 0) * 136 + m] = (f16)k4.x;
            kvT[(dh2 + k * 4 + 1) * 136 + m] = (f16)k4.y;
            kvT[(dh2 + k * 4 + 2) * 136 + m] = (f16)k4.z;
            kvT[(dh2 + k * 4 + 3) * 136 + m] = (f16)k4.w;
        }
    }
    __syncthreads();

    {
        // denom: 512 threads, each sums 32 of 128 m-terms for one n
        const int n = t >> 2, mh = (t & 3) * 32;
        float p = 0.f;
        #pragma unroll
        for (int k = 0; k < 4; ++k) {
            f16x8 pv = *(const f16x8*)&Pn[n * 136 + mh + k * 8];
            #pragma unroll
            for (int e = 0; e < 8; ++e)
                p += (float)pv[e] * ssm[mh + k * 8 + e];
        }
        p += __shfl_xor(p, 1, 64);
        p += __shfl_xor(p, 2, 64);
        if ((t & 3) == 0) dns[n] = (p < 1e-12f) ? 1e-12f : p;
    }
    __syncthreads();

    f32x4 acc3[2][2] = {};
    #pragma unroll
    for (int kt = 0; kt < 4; ++kt) {
        const int kb = kt * 32 + (lane >> 4) * 8;
        f16x8 af3[2], bf3[2];
        #pragma unroll
        for (int i = 0; i < 2; ++i)
            af3[i] = *(const f16x8*)&Pn[(wm * 32 + i * 16 + (lane & 15)) * 136 + kb];
        #pragma unroll
        for (int j = 0; j < 2; ++j)
            bf3[j] = *(const f16x8*)&kvT[(wn * 32 + j * 16 + (lane & 15)) * 136 + kb];
        #pragma unroll
        for (int i = 0; i < 2; ++i)
            #pragma unroll
            for (int j = 0; j < 2; ++j)
                acc3[i][j] = __builtin_amdgcn_mfma_f32_16x16x32_f16(af3[i], bf3[j], acc3[i][j], 0, 0, 0);
    }

    f16* ob = ohA + ((size_t)(b * PN) + nt * 128) * PC + h * PD;
    #pragma unroll
    for (int i = 0; i < 2; ++i) {
        #pragma unroll
        for (int j = 0; j < 2; ++j) {
            const int d = wn * 32 + j * 16 + cc;
            #pragma unroll
            for (int r = 0; r < 4; ++r) {
                const int n = wm * 32 + i * 16 + quad * 4 + r;
                ob[(size_t)n * PC + d] = (f16)(acc3[i][j][r] / dns[n]);
            }
        }
    }
}

// ---------------- output projection GEMM: 64x128 tile, 256t/4 waves (r6 recipe) ----------------
// Same structure as r6 gemm_qkv (proven -25%): per-wave 32x64 output, 16
// MFMA/K-step (NOT the r5-failed 8), 24KB LDS, ~48 VGPR -> ~5 blocks/CU.
__global__ __launch_bounds__(256) void gemm_proj(
        const f16* __restrict__ A,    // [8192][768]
        const f16* __restrict__ Bm,   // [768][768]
        float* __restrict__ Cm, const float* __restrict__ bias)
{
    __shared__ f16 As[64 * 64];
    __shared__ f16 Bs[128 * 64];
    const int t = threadIdx.x;
    const int wave = t >> 6, lane = t & 63;
    const int wm = wave >> 1, wn = wave & 1;     // 2M x 2N, wave owns 32x64
    const int bi = blockIdx.x * 64, bj = blockIdx.y * 128;

    f32x4 acc[2][4] = {};

    const int rowi = lane >> 3;
    const int cb = (lane & 7) ^ ((lane >> 4) & 3);
    const f16* ApE = A + (size_t)(bi + wave * 16 + rowi) * PC + cb * 8;
    const f16* ApO = A + (size_t)(bi + wave * 16 + rowi) * PC + (cb ^ 4) * 8;
    const f16* BpE = Bm + (size_t)(bj + wave * 32 + rowi) * PC + cb * 8;
    const f16* BpO = Bm + (size_t)(bj + wave * 32 + rowi) * PC + (cb ^ 4) * 8;
    f16* AsB = &As[wave * 16 * 64];
    f16* BsB = &Bs[wave * 32 * 64];

    const int q4 = lane >> 4;
    for (int kt = 0; kt < 12; ++kt) {
        const int k0 = kt * 64;
        __syncthreads();
        GLL(ApE + k0,                   AsB);
        GLL(ApO + k0 + (size_t) 8 * PC, AsB + 8 * 64);
        GLL(BpE + k0,                   BsB);
        GLL(BpO + k0 + (size_t) 8 * PC, BsB + 8 * 64);
        GLL(BpE + k0 + (size_t)16 * PC, BsB + 16 * 64);
        GLL(BpO + k0 + (size_t)24 * PC, BsB + 24 * 64);
        __syncthreads();

        #pragma unroll
        for (int kh = 0; kh < 2; ++kh) {
            f16x8 af[2], bf[4];
            #pragma unroll
            for (int i = 0; i < 2; ++i) {
                const int r = wm * 32 + i * 16 + (lane & 15);
                const int p = (kh * 4 + q4) ^ ((r >> 1) & 7);
                af[i] = *(const f16x8*)&As[r * 64 + p * 8];
            }
            #pragma unroll
            for (int j = 0; j < 4; ++j) {
                const int r = wn * 64 + j * 16 + (lane & 15);
                const int p = (kh * 4 + q4) ^ ((r >> 1) & 7);
                bf[j] = *(const f16x8*)&Bs[r * 64 + p * 8];
            }
            #pragma unroll
            for (int i = 0; i < 2; ++i)
                #pragma unroll
                for (int j = 0; j < 4; ++j)
                    acc[i][j] = __builtin_amdgcn_mfma_f32_16x16x32_f16(af[i], bf[j], acc[i][j], 0, 0, 0);
        }
    }

    const int cr = (lane >> 4) * 4, cc = lane & 15;
    #pragma unroll
    for (int i = 0; i < 2; ++i) {
        const int row = bi + wm * 32 + i * 16 + cr;
        #pragma unroll
        for (int j = 0; j < 4; ++j) {
            const int col = bj + wn * 64 + j * 16 + cc;
            const float bv = bias[col];
            #pragma unroll
            for (int r = 0; r < 4; ++r)
                Cm[(size_t)(row + r) * PC + col] = acc[i][j][r] + bv;
        }
    }
}

extern "C" void kernel_launch(void* const* d_in, const int* in_sizes, int n_in,
                              void* d_out, int out_size, void* d_ws, size_t ws_size,
                              hipStream_t stream) {
    const float* x      = (const float*)d_in[0];
    const float* qkv_w  = (const float*)d_in[1];
    const float* proj_w = (const float*)d_in[2];
    const float* proj_b = (const float*)d_in[3];
    const float* rm     = (const float*)d_in[4];
    float* out = (float*)d_out;

    char* ws = (char*)d_ws;
    f16*   Ax   = (f16*)(ws);                     // [8192][768]      = 12,582,912
    f16*   Bqk  = (f16*)(ws + 12582912);          // [2304][768]      =  3,538,944
    f16*   Bp   = (f16*)(ws + 16121856);          // [768][768]       =  1,179,648
    f16*   Rt   = (f16*)(ws + 17301504);          // [12][128][64]    =    196,608
    f16*   zq   = (f16*)(ws + 17498112);          // [96][1024][64]   = 12,582,912
    f16*   zk   = (f16*)(ws + 30081024);          // [96][1024][64]   = 12,582,912
    f16*   vh   = (f16*)(ws + 42663936);          // [96][1024][64]   = 12,582,912
    float* sqq  = (float*)(ws + 55246848);        // [96][1024] f32   =    393,216
    float* sqk  = (float*)(ws + 55640064);        // [96][1024] f32   =    393,216
    float* kvf  = (float*)(ws + 56033280);        // [96][128][64] f32=  3,145,728
    float* sf   = (float*)(ws + 59179008);        // [96][128] f32    =     49,152
    f16*   ohA  = (f16*)(ws + 59228160);          // [8192][768]      = 12,582,912

    // partial-kv buffers ALIAS dead regions (no extra workspace):
    //   kvpA (nt 0-3) -> Ax region (dead after gemm_qkv)
    //   kvpB (nt 4-7) -> ohA region (not live until feat_apply, after kv_reduce)
    //   sfp           -> Bqk region (dead after gemm_qkv)
    float* kvpA = (float*)(ws);                   // 4 * 96*128*64 f32 = 12,582,912
    float* kvpB = (float*)(ws + 59228160);        // 4 * 96*128*64 f32 = 12,582,912
    float* sfp  = (float*)(ws + 12582912);        // [8][96][128] f32  =    393,216

    // 1) conversions
    conv_all<<<11276, 192, 0, stream>>>(x, qkv_w, proj_w, rm, Ax, Bqk, Bp, Rt);

    // 2) fused qkv projection (64x128 tile, 256t, max co-residency)
    gemm_qkv<<<dim3(128, 18), 256, 0, stream>>>(Ax, Bqk, zq, zk, vh, sqq, sqk);

    // 3) fused feat(k) + kf^T@V + colsum -> per-nt partials (8-wave, packed P)
    feat_kv<<<dim3(8, 96), 512, 0, stream>>>(zk, Rt, sqk, vh, kvpA, kvpB, sfp);

    // 4) reduce partials -> kvf, sf
    kv_reduce<<<dim3(96, 9), 256, 0, stream>>>(kvpA, kvpB, sfp, kvf, sf);

    // 5) fused feat(q) + denom + P@KV -> ohA (8-wave, swapped MFMA1, packed P)
    feat_apply<<<dim3(8, 96), 512, 0, stream>>>(zq, Rt, sqq, kvf, sf, ohA);

    // 6) out = oh @ proj_w^T + proj_b (64x128 tile, r6 recipe)
    gemm_proj<<<dim3(128, 6), 256, 0, stream>>>(ohA, Bp, out, proj_b);
}